// Round 13
// baseline (1955.588 us; speedup 1.0000x reference)
//
#include <hip/hip_runtime.h>
#include <hip/hip_bf16.h>
#include <math.h>

#define BSZ 32
#define SEQ 512
#define DIM 512
#define NH 8
#define DKH 64
#define DFFN 2048
#define NL 2
#define KIDX 5
#define NEGV -1e32f

typedef float f32x4 __attribute__((ext_vector_type(4)));
typedef short bf16x8 __attribute__((ext_vector_type(8)));
typedef unsigned short ushort_t;
typedef __attribute__((address_space(1))) void gvoid;
typedef __attribute__((address_space(3))) void lvoid;

// async global->LDS, 16B per lane; dest is wave-uniform base (+lane*16 by HW)
__device__ __forceinline__ void gload_lds16(const void* g, void* l) {
    __builtin_amdgcn_global_load_lds((gvoid*)(uintptr_t)g, (lvoid*)l, 16, 0, 0);
}

// ---------------- wave (64-lane) reduce helpers ----------------
__device__ __forceinline__ float wmaxf(float v) {
    #pragma unroll
    for (int m = 32; m > 0; m >>= 1) v = fmaxf(v, __shfl_xor(v, m));
    return v;
}
__device__ __forceinline__ float wsumf(float v) {
    #pragma unroll
    for (int m = 32; m > 0; m >>= 1) v += __shfl_xor(v, m);
    return v;
}
__device__ __forceinline__ int wsumi(int v) {
    #pragma unroll
    for (int m = 32; m > 0; m >>= 1) v += __shfl_xor(v, m);
    return v;
}

// ---------------- bf16 split helpers ----------------
__device__ __forceinline__ unsigned int bf16_rne(float x) {
    unsigned int u = __float_as_uint(x);
    return (u + 0x7fffu + ((u >> 16) & 1u)) >> 16;
}
__device__ __forceinline__ void split3_8(const float* xs, unsigned int* hh,
                                         unsigned int* hm, unsigned int* hl) {
    #pragma unroll
    for (int e = 0; e < 8; e++) {
        float x = xs[e];
        unsigned int h0 = bf16_rne(x);
        float r1 = x - __uint_as_float(h0 << 16);
        unsigned int h1 = bf16_rne(r1);
        float r2 = r1 - __uint_as_float(h1 << 16);
        hh[e] = h0; hm[e] = h1; hl[e] = bf16_rne(r2);
    }
}
__device__ __forceinline__ uint4 pack8(const unsigned int* h) {
    return make_uint4(h[0] | (h[1] << 16), h[2] | (h[3] << 16),
                      h[4] | (h[5] << 16), h[6] | (h[7] << 16));
}

__device__ __forceinline__ f32x4 mfma_bf16(bf16x8 a, bf16x8 b, f32x4 c) {
    return __builtin_amdgcn_mfma_f32_16x16x32_bf16(a, b, c, 0, 0, 0);
}

// ---------------- add_pe: x fp32 + y planes ----------------
__global__ void add_pe_new(const float* __restrict__ q, const float* __restrict__ qa,
                           const float* __restrict__ pe, float* __restrict__ x,
                           ushort_t* __restrict__ ypl, size_t yelems, int n8) {
    int i = blockIdx.x * 256 + threadIdx.x;
    if (i >= n8) return;
    size_t base = (size_t)i * 8;
    size_t pb = base & (size_t)(SEQ * DIM - 1);
    float4 a0 = *(const float4*)(q + base), a1 = *(const float4*)(q + base + 4);
    float4 b0 = *(const float4*)(qa + base), b1 = *(const float4*)(qa + base + 4);
    float4 p0 = *(const float4*)(pe + pb), p1 = *(const float4*)(pe + pb + 4);
    float4 x0 = make_float4(a0.x + p0.x, a0.y + p0.y, a0.z + p0.z, a0.w + p0.w);
    float4 x1 = make_float4(a1.x + p1.x, a1.y + p1.y, a1.z + p1.z, a1.w + p1.w);
    *(float4*)(x + base) = x0;
    *(float4*)(x + base + 4) = x1;
    float ys[8] = {b0.x + p0.x, b0.y + p0.y, b0.z + p0.z, b0.w + p0.w,
                   b1.x + p1.x, b1.y + p1.y, b1.z + p1.z, b1.w + p1.w};
    unsigned int hh[8], hm[8], hl[8];
    split3_8(ys, hh, hm, hl);
    *(uint4*)(ypl + base) = pack8(hh);
    *(uint4*)(ypl + yelems + base) = pack8(hm);
    *(uint4*)(ypl + 2 * yelems + base) = pack8(hl);
}

// ---------------- weight pre-split: fp32 -> 3 bf16 planes ----------------
__global__ void split3w(const float* __restrict__ W, ushort_t* __restrict__ out,
                        size_t elems, int n8) {
    int i = blockIdx.x * 256 + threadIdx.x;
    if (i >= n8) return;
    size_t base = (size_t)i * 8;
    float4 a0 = *(const float4*)(W + base), a1 = *(const float4*)(W + base + 4);
    float xs[8] = {a0.x, a0.y, a0.z, a0.w, a1.x, a1.y, a1.z, a1.w};
    unsigned int hh[8], hm[8], hl[8];
    split3_8(xs, hh, hm, hl);
    *(uint4*)(out + base) = pack8(hh);
    *(uint4*)(out + elems + base) = pack8(hm);
    *(uint4*)(out + 2 * elems + base) = pack8(hl);
}

// ---------------- fp32 vector GEMM (selection-critical layer-1 q; exact chains) ----------------
template <int RELU>
__global__ __launch_bounds__(256)
void gemm_bt(const float* __restrict__ A, const float* __restrict__ B,
             const float* __restrict__ bias, float* __restrict__ C,
             int M, int N, int K) {
    __shared__ float As[32][132];
    __shared__ float Bs[32][132];
    const int tid = threadIdx.x;
    const int tx = tid & 15, ty = tid >> 4;
    const int m0 = blockIdx.y * 128, n0 = blockIdx.x * 128;
    float acc[8][8] = {};
    for (int k0 = 0; k0 < K; k0 += 32) {
        #pragma unroll
        for (int s = tid; s < 1024; s += 256) {
            int r = (s & 15) | ((s >> 7) << 4);
            int c4 = (s >> 4) & 7;
            float4 va = *(const float4*)(A + (size_t)(m0 + r) * K + k0 + c4 * 4);
            As[c4 * 4 + 0][r] = va.x; As[c4 * 4 + 1][r] = va.y;
            As[c4 * 4 + 2][r] = va.z; As[c4 * 4 + 3][r] = va.w;
            float4 vb = *(const float4*)(B + (size_t)(n0 + r) * K + k0 + c4 * 4);
            Bs[c4 * 4 + 0][r] = vb.x; Bs[c4 * 4 + 1][r] = vb.y;
            Bs[c4 * 4 + 2][r] = vb.z; Bs[c4 * 4 + 3][r] = vb.w;
        }
        __syncthreads();
        #pragma unroll 8
        for (int kk = 0; kk < 32; kk++) {
            float a[8], b[8];
            *(float4*)&a[0] = *(const float4*)&As[kk][ty * 8];
            *(float4*)&a[4] = *(const float4*)&As[kk][ty * 8 + 4];
            *(float4*)&b[0] = *(const float4*)&Bs[kk][tx * 8];
            *(float4*)&b[4] = *(const float4*)&Bs[kk][tx * 8 + 4];
            #pragma unroll
            for (int i = 0; i < 8; i++)
                #pragma unroll
                for (int j = 0; j < 8; j++)
                    acc[i][j] = fmaf(a[i], b[j], acc[i][j]);
        }
        __syncthreads();
    }
    float bv[8];
    *(float4*)&bv[0] = *(const float4*)(bias + n0 + tx * 8);
    *(float4*)&bv[4] = *(const float4*)(bias + n0 + tx * 8 + 4);
    #pragma unroll
    for (int i = 0; i < 8; i++) {
        float out[8];
        #pragma unroll
        for (int j = 0; j < 8; j++) {
            float v = acc[i][j] + bv[j];
            if (RELU) v = fmaxf(v, 0.f);
            out[j] = v;
        }
        float* cp = C + (size_t)(m0 + ty * 8 + i) * N + n0 + tx * 8;
        *(float4*)cp = *(float4*)&out[0];
        *(float4*)(cp + 4) = *(float4*)&out[4];
    }
}

// ---------------- fp32 scores (selection-critical, round-1 arithmetic) ----------------
__global__ __launch_bounds__(256)
void scores128_kernel(const float* __restrict__ q, float* __restrict__ pbuf) {
    const int bh = blockIdx.y, b = bh >> 3, h = bh & 7;
    const int x = blockIdx.x;
    const int it = (x >= 6) ? 3 : (x >= 3) ? 2 : (x >= 1) ? 1 : 0;
    const int jt = x - it * (it + 1) / 2;
    const int m0 = it * 128, n0 = jt * 128;
    __shared__ float Qi[64][132];
    __shared__ float Qj[64][132];
    const float* qbase = q + (size_t)b * SEQ * DIM + h * DKH;
    const int tid = threadIdx.x;
    for (int s = tid; s < 2048; s += 256) {
        int row = (s & 15) | ((s >> 8) << 4);
        int c4 = (s >> 4) & 15;
        float4 vi = *(const float4*)(qbase + (size_t)(m0 + row) * DIM + c4 * 4);
        Qi[c4 * 4 + 0][row] = vi.x; Qi[c4 * 4 + 1][row] = vi.y;
        Qi[c4 * 4 + 2][row] = vi.z; Qi[c4 * 4 + 3][row] = vi.w;
        float4 vj = *(const float4*)(qbase + (size_t)(n0 + row) * DIM + c4 * 4);
        Qj[c4 * 4 + 0][row] = vj.x; Qj[c4 * 4 + 1][row] = vj.y;
        Qj[c4 * 4 + 2][row] = vj.z; Qj[c4 * 4 + 3][row] = vj.w;
    }
    __syncthreads();
    const int tx = tid & 15, ty = tid >> 4;
    float acc[8][8] = {};
    #pragma unroll 4
    for (int d = 0; d < 64; d++) {
        float a[8], bb[8];
        *(float4*)&a[0] = *(const float4*)&Qi[d][ty * 8];
        *(float4*)&a[4] = *(const float4*)&Qi[d][ty * 8 + 4];
        *(float4*)&bb[0] = *(const float4*)&Qj[d][tx * 8];
        *(float4*)&bb[4] = *(const float4*)&Qj[d][tx * 8 + 4];
        #pragma unroll
        for (int i = 0; i < 8; i++)
            #pragma unroll
            for (int j = 0; j < 8; j++)
                acc[i][j] = fmaf(a[i], bb[j], acc[i][j]);
    }
    float* prow = pbuf + ((size_t)bh * SEQ + m0) * SEQ + n0;
    #pragma unroll
    for (int i = 0; i < 8; i++) {
        int gi = m0 + ty * 8 + i;
        #pragma unroll
        for (int jq = 0; jq < 2; jq++) {
            float o[4];
            #pragma unroll
            for (int j = 0; j < 4; j++) {
                int gj = n0 + tx * 8 + jq * 4 + j;
                o[j] = (gj < gi) ? acc[i][jq * 4 + j] * 0.125f : NEGV;
            }
            *(float4*)(prow + (size_t)(ty * 8 + i) * SEQ + tx * 8 + jq * 4) = *(float4*)o;
        }
    }
}

// ---------------- lean NP-plane bf16 GEMM (pre-split operands, async staging) ----------------
template <int RELU, int OUTP, int NP>
__global__ __launch_bounds__(256) void gemm3p(
    const ushort_t* __restrict__ Apl, size_t Aelems, int lda,
    const ushort_t* __restrict__ Bpl, size_t Belems, int ldb,
    const float* __restrict__ bias,
    float* __restrict__ C, ushort_t* __restrict__ Cpl, size_t Celems,
    int ldc, int K) {
    constexpr int BB = NP * 512;               // uint4 idx of B region
    __shared__ uint4 lds[2 * NP * 512];
    const int tid = threadIdx.x, lane = tid & 63, wid = tid >> 6;
    const int wm = wid >> 1, wn = wid & 1;
    const int m0 = blockIdx.y * 128, n0 = blockIdx.x * 128;
    const int lrow = lane & 15, lkof = (lane >> 4) * 8;
    f32x4 acc[4][4] = {};
    for (int k0 = 0; k0 < K; k0 += 32) {
        #pragma unroll
        for (int t = 0; t < 4 * NP; t++) {
            int cc = wid + t * 4;              // 0 .. 16*NP-1
            bool isB = cc >= 8 * NP;
            int c2 = isB ? (cc - 8 * NP) : cc;
            int p = c2 >> 3, fi = c2 & 7;
            const ushort_t* pb = isB ? (Bpl + (size_t)p * Belems) : (Apl + (size_t)p * Aelems);
            int ld = isB ? ldb : lda;
            int r0 = isB ? n0 : m0;
            const ushort_t* src = pb + (size_t)(r0 + fi * 16 + lrow) * ld + k0 + lkof;
            gload_lds16(src, &lds[(isB ? BB : 0) + p * 512 + fi * 64]);
        }
        __syncthreads();
        const bf16x8* ldsb = (const bf16x8*)lds;
        bf16x8 afr[4][NP];
        #pragma unroll
        for (int fm = 0; fm < 4; fm++)
            #pragma unroll
            for (int p = 0; p < NP; p++)
                afr[fm][p] = ldsb[p * 512 + (wm * 4 + fm) * 64 + lane];
        #pragma unroll
        for (int fn = 0; fn < 4; fn++) {
            bf16x8 b0 = ldsb[BB + 0 * 512 + (wn * 4 + fn) * 64 + lane];
            bf16x8 b1 = ldsb[BB + 1 * 512 + (wn * 4 + fn) * 64 + lane];
            bf16x8 b2;
            if constexpr (NP == 3) b2 = ldsb[BB + 2 * 512 + (wn * 4 + fn) * 64 + lane];
            #pragma unroll
            for (int fm = 0; fm < 4; fm++) {
                f32x4 t = acc[fm][fn];
                if constexpr (NP == 3) {
                    t = mfma_bf16(afr[fm][0], b0, t);
                    t = mfma_bf16(afr[fm][1], b0, t);
                    t = mfma_bf16(afr[fm][2], b0, t);
                    t = mfma_bf16(afr[fm][0], b1, t);
                    t = mfma_bf16(afr[fm][1], b1, t);
                    t = mfma_bf16(afr[fm][0], b2, t);
                } else {
                    t = mfma_bf16(afr[fm][0], b0, t);
                    t = mfma_bf16(afr[fm][1], b0, t);
                    t = mfma_bf16(afr[fm][0], b1, t);
                }
                acc[fm][fn] = t;
            }
        }
        __syncthreads();
    }
    #pragma unroll
    for (int fm = 0; fm < 4; fm++) {
        int row0 = m0 + (wm * 4 + fm) * 16 + (lane >> 4) * 4;
        #pragma unroll
        for (int fn = 0; fn < 4; fn++) {
            int col = n0 + (wn * 4 + fn) * 16 + (lane & 15);
            float bv = bias[col];
            f32x4 a = acc[fm][fn];
            #pragma unroll
            for (int r = 0; r < 4; r++) {
                int row = row0 + r;
                float val = a[r] + bv;
                if (RELU) val = fmaxf(val, 0.f);
                if constexpr (OUTP == 0) {
                    C[(size_t)row * ldc + col] = val;
                } else {
                    unsigned int h0 = bf16_rne(val);
                    float r1 = val - __uint_as_float(h0 << 16);
                    unsigned int h1 = bf16_rne(r1);
                    size_t o = (size_t)row * ldc + col;
                    Cpl[o] = (ushort_t)h0;
                    Cpl[Celems + o] = (ushort_t)h1;
                    if constexpr (NP == 3) {
                        float r2 = r1 - __uint_as_float(h1 << 16);
                        Cpl[2 * Celems + o] = (ushort_t)bf16_rne(r2);
                    }
                }
            }
        }
    }
}

// ---------------- AV with NP-plane output (in-kernel split staging) ----------------
template <int NP>
__global__ __launch_bounds__(256) void mm6av_pl(const float* __restrict__ pbuf,
                                                const float* __restrict__ vt,
                                                ushort_t* __restrict__ Opl, size_t Oelems) {
    constexpr int BBASE = NP * 512;
    __shared__ uint4 lds[NP * 512 + NP * 256];
    const int tid = threadIdx.x, lane = tid & 63, wid = tid >> 6;
    const int bh = blockIdx.y, b = bh >> 3, h = bh & 7, rb = blockIdx.x;
    const int m0 = rb * 128;
    const float* A = pbuf + (size_t)bh * SEQ * SEQ;
    const float* B = vt + (size_t)bh * DKH * SEQ;
    const int kmax = rb ? (rb + 1) * 128 : SEQ;

    f32x4 acc[2][4] = {};
    for (int k0 = 0; k0 < kmax; k0 += 32) {
        for (int c = tid; c < 12 * 64; c += 256) {
            int fi = c >> 6, lc = c & 63;
            const float* src = (fi < 8)
                ? A + (size_t)(m0 + fi * 16 + (lc & 15)) * SEQ + k0 + (lc >> 4) * 8
                : B + (size_t)((fi - 8) * 16 + (lc & 15)) * SEQ + k0 + (lc >> 4) * 8;
            float4 x0 = *(const float4*)src;
            float4 x1 = *(const float4*)(src + 4);
            float xs[8] = {x0.x, x0.y, x0.z, x0.w, x1.x, x1.y, x1.z, x1.w};
            unsigned int hh[8], hm[8], hl[8];
            split3_8(xs, hh, hm, hl);
            int base, fstride;
            if (fi < 8) { base = fi * 64 + lc; fstride = 512; }
            else { base = BBASE + (fi - 8) * 64 + lc; fstride = 256; }
            lds[base] = pack8(hh);
            lds[base + fstride] = pack8(hm);
            if (NP == 3) lds[base + 2 * fstride] = pack8(hl);
        }
        __syncthreads();
        const bf16x8* ldsb = (const bf16x8*)lds;
        bf16x8 afr[2][NP];
        #pragma unroll
        for (int fm = 0; fm < 2; fm++)
            #pragma unroll
            for (int p = 0; p < NP; p++)
                afr[fm][p] = ldsb[p * 512 + (wid * 2 + fm) * 64 + lane];
        #pragma unroll
        for (int fn = 0; fn < 4; fn++) {
            bf16x8 b0 = ldsb[BBASE + 0 * 256 + fn * 64 + lane];
            bf16x8 b1 = ldsb[BBASE + 1 * 256 + fn * 64 + lane];
            bf16x8 b2;
            if constexpr (NP == 3) b2 = ldsb[BBASE + 2 * 256 + fn * 64 + lane];
            #pragma unroll
            for (int fm = 0; fm < 2; fm++) {
                f32x4 t = acc[fm][fn];
                if constexpr (NP == 3) {
                    t = mfma_bf16(afr[fm][0], b0, t);
                    t = mfma_bf16(afr[fm][1], b0, t);
                    t = mfma_bf16(afr[fm][2], b0, t);
                    t = mfma_bf16(afr[fm][0], b1, t);
                    t = mfma_bf16(afr[fm][1], b1, t);
                    t = mfma_bf16(afr[fm][0], b2, t);
                } else {
                    t = mfma_bf16(afr[fm][0], b0, t);
                    t = mfma_bf16(afr[fm][1], b0, t);
                    t = mfma_bf16(afr[fm][0], b1, t);
                }
                acc[fm][fn] = t;
            }
        }
        __syncthreads();
    }
    #pragma unroll
    for (int fm = 0; fm < 2; fm++) {
        int row0 = m0 + (wid * 2 + fm) * 16 + (lane >> 4) * 4;
        #pragma unroll
        for (int fn = 0; fn < 4; fn++) {
            int col = fn * 16 + (lane & 15);
            f32x4 a = acc[fm][fn];
            #pragma unroll
            for (int r = 0; r < 4; r++) {
                int row = row0 + r;
                float val = (row == 0) ? 0.f : a[r];
                unsigned int h0 = bf16_rne(val);
                float r1 = val - __uint_as_float(h0 << 16);
                unsigned int h1 = bf16_rne(r1);
                size_t o = ((size_t)b * SEQ + row) * DIM + h * DKH + col;
                Opl[o] = (ushort_t)h0;
                Opl[Oelems + o] = (ushort_t)h1;
                if constexpr (NP == 3) {
                    float r2 = r1 - __uint_as_float(h1 << 16);
                    Opl[2 * Oelems + o] = (ushort_t)bf16_rne(r2);
                }
            }
        }
    }
}

// ---------------- V transpose ----------------
__global__ __launch_bounds__(256) void transpose_v_kernel(const float* __restrict__ v,
                                                          float* __restrict__ vt) {
    const int bh = blockIdx.y, jt = blockIdx.x;
    const int b = bh >> 3, h = bh & 7;
    __shared__ float L[64][65];
    const int tid = threadIdx.x;
    for (int s = tid; s < 1024; s += 256) {
        int jj = s >> 4, d4 = s & 15;
        float4 x = *(const float4*)(v + ((size_t)(b * SEQ) + jt * 64 + jj) * DIM + h * DKH + d4 * 4);
        L[jj][d4 * 4 + 0] = x.x; L[jj][d4 * 4 + 1] = x.y;
        L[jj][d4 * 4 + 2] = x.z; L[jj][d4 * 4 + 3] = x.w;
    }
    __syncthreads();
    int d = tid >> 2, jq = tid & 3;
    float* dst = vt + ((size_t)bh * DKH + d) * SEQ + jt * 64 + jq * 16;
    #pragma unroll
    for (int c4 = 0; c4 < 4; c4++) {
        float4 o = make_float4(L[jq * 16 + c4 * 4 + 0][d], L[jq * 16 + c4 * 4 + 1][d],
                               L[jq * 16 + c4 * 4 + 2][d], L[jq * 16 + c4 * 4 + 3][d]);
        *(float4*)(dst + c4 * 4) = o;
    }
}

// ---------------- softmax -> top5 -> second softmax (4 rows per 256-thread block) ----------------
__global__ __launch_bounds__(256)
void softmax_topk_kernel(float* __restrict__ pbuf) {
    const int wid = threadIdx.x >> 6, lane = threadIdx.x & 63;
    const int i = blockIdx.x * 4 + wid;
    const size_t row = (size_t)blockIdx.y * SEQ + i;
    float* p = pbuf + row * SEQ;
    float v[8];
    {
        int j0 = lane * 4;
        if (j0 < i) {
            float4 x0 = *(const float4*)(p + j0);
            v[0] = (j0 + 0 < i) ? x0.x : NEGV;
            v[1] = (j0 + 1 < i) ? x0.y : NEGV;
            v[2] = (j0 + 2 < i) ? x0.z : NEGV;
            v[3] = (j0 + 3 < i) ? x0.w : NEGV;
        } else { v[0] = v[1] = v[2] = v[3] = NEGV; }
        int j1 = 256 + j0;
        if (j1 < i) {
            float4 x1 = *(const float4*)(p + j1);
            v[4] = (j1 + 0 < i) ? x1.x : NEGV;
            v[5] = (j1 + 1 < i) ? x1.y : NEGV;
            v[6] = (j1 + 2 < i) ? x1.z : NEGV;
            v[7] = (j1 + 3 < i) ? x1.w : NEGV;
        } else { v[4] = v[5] = v[6] = v[7] = NEGV; }
    }
    float lm = v[0];
    #pragma unroll
    for (int e = 1; e < 8; e++) lm = fmaxf(lm, v[e]);
    float m1 = wmaxf(lm);
    float ls = 0.f;
    #pragma unroll
    for (int e = 0; e < 8; e++) { v[e] = expf(v[e] - m1); ls += v[e]; }
    float Z = wsumf(ls);
    #pragma unroll
    for (int e = 0; e < 8; e++) v[e] = v[e] / Z;
    float thr = -INFINITY;
    if (i >= KIDX) {
        int remaining = KIDX;
        float cut = INFINITY;
        #pragma unroll 1
        for (int iter = 0; iter < KIDX; iter++) {
            float l2 = -INFINITY;
            #pragma unroll
            for (int e = 0; e < 8; e++) if (v[e] < cut) l2 = fmaxf(l2, v[e]);
            float m2 = wmaxf(l2);
            int lc = 0;
            #pragma unroll
            for (int e = 0; e < 8; e++) if (v[e] == m2) lc++;
            int c = wsumi(lc);
            if (c >= remaining) { thr = m2; break; }
            remaining -= c; cut = m2;
        }
    }
    float lpm = v[0];
    #pragma unroll
    for (int e = 1; e < 8; e++) lpm = fmaxf(lpm, v[e]);
    float pm = wmaxf(lpm);
    float t[8];
    float ls2 = 0.f;
    #pragma unroll
    for (int e = 0; e < 8; e++) {
        bool keep = (i >= KIDX) ? (v[e] >= thr) : true;
        t[e] = keep ? expf(v[e] - pm) : 0.f;
        ls2 += t[e];
    }
    float Z2 = wsumf(ls2);
    #pragma unroll
    for (int e = 0; e < 8; e++) t[e] = t[e] / Z2;
    *(float4*)(p + lane * 4) = make_float4(t[0], t[1], t[2], t[3]);
    *(float4*)(p + 256 + lane * 4) = make_float4(t[4], t[5], t[6], t[7]);
}

// ---------------- dst = LN(x + t)  (EMIT: also write 3 bf16 planes of dst) ----------------
template <int EMIT>
__global__ __launch_bounds__(64)
void add_ln_kernel(const float* __restrict__ x, const float* __restrict__ t,
                   const float* __restrict__ w, const float* __restrict__ b,
                   float* __restrict__ dst, ushort_t* __restrict__ dpl, size_t delems) {
    const size_t row = blockIdx.x;
    const int lane = threadIdx.x;
    const float* xr = x + row * DIM;
    const float* tr = t + row * DIM;
    float v[8];
    {
        float4 a0 = *(const float4*)(xr + lane * 4);
        float4 t0 = *(const float4*)(tr + lane * 4);
        float4 a1 = *(const float4*)(xr + 256 + lane * 4);
        float4 t1 = *(const float4*)(tr + 256 + lane * 4);
        v[0] = a0.x + t0.x; v[1] = a0.y + t0.y; v[2] = a0.z + t0.z; v[3] = a0.w + t0.w;
        v[4] = a1.x + t1.x; v[5] = a1.y + t1.y; v[6] = a1.z + t1.z; v[7] = a1.w + t1.w;
    }
    float ls = 0.f;
    #pragma unroll
    for (int e = 0; e < 8; e++) ls += v[e];
    float mean = wsumf(ls) / (float)DIM;
    float ld = 0.f;
    #pragma unroll
    for (int e = 0; e < 8; e++) { float d = v[e] - mean; ld += d * d; }
    float var = wsumf(ld) / (float)DIM;
    float den = sqrtf(var + 1e-5f);
    float wv[8], bv[8];
    *(float4*)&wv[0] = *(const float4*)(w + lane * 4);
    *(float4*)&wv[4] = *(const float4*)(w + 256 + lane * 4);
    *(float4*)&bv[0] = *(const float4*)(b + lane * 4);
    *(float4*)&bv[4] = *(const float4*)(b + 256 + lane * 4);
    float o[8];
    #pragma unroll
    for (int e = 0; e < 8; e++) o[e] = (v[e] - mean) / den * wv[e] + bv[e];
    float* dr = dst + row * DIM;
    *(float4*)(dr + lane * 4) = make_float4(o[0], o[1], o[2], o[3]);
    *(float4*)(dr + 256 + lane * 4) = make_float4(o[4], o[5], o[6], o[7]);
    if constexpr (EMIT) {
        unsigned int hh[8], hm[8], hl[8];
        split3_8(o, hh, hm, hl);
        size_t base0 = row * DIM + lane * 4;
        size_t base1 = base0 + 256;
        #pragma unroll
        for (int p = 0; p < 3; p++) {
            const unsigned int* hp = (p == 0) ? hh : (p == 1) ? hm : hl;
            *(uint2*)(dpl + p * delems + base0) =
                make_uint2(hp[0] | (hp[1] << 16), hp[2] | (hp[3] << 16));
            *(uint2*)(dpl + p * delems + base1) =
                make_uint2(hp[4] | (hp[5] << 16), hp[6] | (hp[7] << 16));
        }
    }
}

extern "C" void kernel_launch(void* const* d_in, const int* in_sizes, int n_in,
                              void* d_out, int out_size, void* d_ws, size_t ws_size,
                              hipStream_t stream) {
    const float* q_embed = (const float*)d_in[0];
    const float* qa_embed = (const float*)d_in[1];
    const float* pe = (const float*)d_in[2];
    const float* Wk = (const float*)d_in[3];
    const float* bk = (const float*)d_in[4];
    const float* Wv = (const float*)d_in[5];
    const float* bv = (const float*)d_in[6];
    const float* Wo = (const float*)d_in[7];
    const float* bo = (const float*)d_in[8];
    const float* W1 = (const float*)d_in[9];
    const float* b1 = (const float*)d_in[10];
    const float* W2 = (const float*)d_in[11];
    const float* b2 = (const float*)d_in[12];
    const float* ln1w = (const float*)d_in[13];
    const float* ln1b = (const float*)d_in[14];
    const float* ln2w = (const float*)d_in[15];
    const float* ln2b = (const float*)d_in[16];

    float* outx = (float*)d_out;
    const size_t NE = (size_t)BSZ * SEQ * DIM;   // 8388608
    float* pbuf = outx + NE;
    float* ws = (float*)d_ws;
    const int M = BSZ * SEQ;

    // ===================== pre-split planes path (round-8 proven layout) =====================
    float* xbuf = ws;
    float* qbuf = ws + NE;
    float* vbuf = ws + 2 * NE;
    ushort_t* y_pl = (ushort_t*)(ws + 3 * NE);
    ushort_t* x_pl = (ushort_t*)(ws + 4 * NE + NE / 2);
    ushort_t* w_pl = (ushort_t*)(ws + 6 * NE);
    float* vt = ws + 7 * NE;
    ushort_t* o_pl = (ushort_t*)(ws + 8 * NE);
    ushort_t* h1_pl = (ushort_t*)(ws + 7 * NE);   // sequential reuse with vt/o_pl
    ushort_t* wk_pl = (ushort_t*)(ws + 13 * NE);  // Wk[1] planes (layer-2 q only)

    const size_t WVE = (size_t)DIM * DIM;      // 262144
    const size_t W1E = (size_t)DFFN * DIM;     // 1048576
    const size_t LW = 3 * (WVE + WVE + W1E + W1E);

    // layer-2 q via split-6 MFMA requires 13NE floats + 3*WVE ushorts of ws
    const bool q2_mfma = ws_size >= (13 * NE * sizeof(float) + 3 * WVE * sizeof(ushort_t));

    for (int l = 0; l < NL; l++) {
        ushort_t* base = w_pl + (size_t)l * LW;
        split3w<<<(int)(WVE / 8 + 255) / 256, 256, 0, stream>>>(
            Wv + (size_t)l * WVE, base, WVE, (int)(WVE / 8));
        split3w<<<(int)(WVE / 8 + 255) / 256, 256, 0, stream>>>(
            Wo + (size_t)l * WVE, base + 3 * WVE, WVE, (int)(WVE / 8));
        split3w<<<(int)(W1E / 8 + 255) / 256, 256, 0, stream>>>(
            W1 + (size_t)l * W1E, base + 6 * WVE, W1E, (int)(W1E / 8));
        split3w<<<(int)(W1E / 8 + 255) / 256, 256, 0, stream>>>(
            W2 + (size_t)l * W1E, base + 6 * WVE + 3 * W1E, W1E, (int)(W1E / 8));
    }
    if (q2_mfma) {
        split3w<<<(int)(WVE / 8 + 255) / 256, 256, 0, stream>>>(
            Wk + 1 * WVE, wk_pl, WVE, (int)(WVE / 8));
    }

    add_pe_new<<<(int)(NE / 8 + 255) / 256, 256, 0, stream>>>(
        q_embed, qa_embed, pe, xbuf, y_pl, NE, (int)(NE / 8));

    for (int l = 0; l < NL; l++) {
        ushort_t* wb = w_pl + (size_t)l * LW;
        ushort_t* Wv_pl = wb;
        ushort_t* Wo_pl = wb + 3 * WVE;
        ushort_t* W1_pl = wb + 6 * WVE;
        ushort_t* W2_pl = wb + 6 * WVE + 3 * W1E;

        // q projection:
        //   layer 1 (l==0): fp32 exact — structural p-tie exists, any noise flips it.
        //   layer 2 (l==1): split-6 MFMA — layer-2 scores already carry ~1e-6 noise
        //   from the split-6 x chain (rounds 4-8 pass), so matching-scale q noise is safe.
        if (l == 1 && q2_mfma) {
            gemm3p<0, 0, 3><<<dim3(DIM / 128, M / 128), 256, 0, stream>>>(
                x_pl, NE, DIM, wk_pl, WVE, DIM, bk + (size_t)l * DIM,
                qbuf, nullptr, 0, DIM, DIM);
        } else {
            gemm_bt<0><<<dim3(DIM / 128, M / 128), 256, 0, stream>>>(
                xbuf, Wk + (size_t)l * WVE, bk + (size_t)l * DIM, qbuf, M, DIM, DIM);
        }
        if (l == 0) {
            gemm3p<0, 0, 3><<<dim3(DIM / 128, M / 128), 256, 0, stream>>>(
                y_pl, NE, DIM, Wv_pl, WVE, DIM, bv + (size_t)l * DIM,
                vbuf, nullptr, 0, DIM, DIM);
        } else {
            gemm3p<0, 0, 2><<<dim3(DIM / 128, M / 128), 256, 0, stream>>>(
                y_pl, NE, DIM, Wv_pl, WVE, DIM, bv + (size_t)l * DIM,
                vbuf, nullptr, 0, DIM, DIM);
        }
        transpose_v_kernel<<<dim3(8, BSZ * NH), 256, 0, stream>>>(vbuf, vt);
        scores128_kernel<<<dim3(10, BSZ * NH), 256, 0, stream>>>(qbuf, pbuf);
        softmax_topk_kernel<<<dim3(SEQ / 4, BSZ * NH), 256, 0, stream>>>(pbuf);
        if (l == 0) {
            mm6av_pl<3><<<dim3(4, BSZ * NH), 256, 0, stream>>>(pbuf, vt, o_pl, NE);
            gemm3p<0, 0, 3><<<dim3(DIM / 128, M / 128), 256, 0, stream>>>(
                o_pl, NE, DIM, Wo_pl, WVE, DIM, bo + (size_t)l * DIM,
                qbuf, nullptr, 0, DIM, DIM);
        } else {
            mm6av_pl<2><<<dim3(4, BSZ * NH), 256, 0, stream>>>(pbuf, vt, o_pl, NE);
            gemm3p<0, 0, 2><<<dim3(DIM / 128, M / 128), 256, 0, stream>>>(
                o_pl, NE, DIM, Wo_pl, WVE, DIM, bo + (size_t)l * DIM,
                qbuf, nullptr, 0, DIM, DIM);
        }
        add_ln_kernel<1><<<M, 64, 0, stream>>>(
            xbuf, qbuf, ln1w + (size_t)l * DIM, ln1b + (size_t)l * DIM,
            xbuf, x_pl, NE);
        if (l == 0) {
            gemm3p<1, 1, 3><<<dim3(DFFN / 128, M / 128), 256, 0, stream>>>(
                x_pl, NE, DIM, W1_pl, W1E, DIM, b1 + (size_t)l * DFFN,
                nullptr, h1_pl, (size_t)M * DFFN, DFFN, DIM);
            gemm3p<0, 0, 3><<<dim3(DIM / 128, M / 128), 256, 0, stream>>>(
                h1_pl, (size_t)M * DFFN, DFFN, W2_pl, W1E, DFFN, b2 + (size_t)l * DIM,
                vbuf, nullptr, 0, DIM, DFFN);
        } else {
            gemm3p<1, 1, 2><<<dim3(DFFN / 128, M / 128), 256, 0, stream>>>(
                x_pl, NE, DIM, W1_pl, W1E, DIM, b1 + (size_t)l * DFFN,
                nullptr, h1_pl, (size_t)M * DFFN, DFFN, DIM);
            gemm3p<0, 0, 2><<<dim3(DIM / 128, M / 128), 256, 0, stream>>>(
                h1_pl, (size_t)M * DFFN, DFFN, W2_pl, W1E, DFFN, b2 + (size_t)l * DIM,
                vbuf, nullptr, 0, DIM, DFFN);
        }
        // x = LN(x + ff); after layer 0 also emit x planes for layer-2's q-projection
        if (l == NL - 1) {
            add_ln_kernel<0><<<M, 64, 0, stream>>>(
                xbuf, vbuf, ln2w + (size_t)l * DIM, ln2b + (size_t)l * DIM,
                outx, nullptr, 0);
        } else if (q2_mfma) {
            add_ln_kernel<1><<<M, 64, 0, stream>>>(
                xbuf, vbuf, ln2w + (size_t)l * DIM, ln2b + (size_t)l * DIM,
                xbuf, x_pl, NE);
        } else {
            add_ln_kernel<0><<<M, 64, 0, stream>>>(
                xbuf, vbuf, ln2w + (size_t)l * DIM, ln2b + (size_t)l * DIM,
                xbuf, nullptr, 0);
        }
    }
}

// Round 15
// 1952.752 us; speedup vs baseline: 1.0015x; 1.0015x over previous
//
#include <hip/hip_runtime.h>
#include <hip/hip_bf16.h>
#include <math.h>

#define BSZ 32
#define SEQ 512
#define DIM 512
#define NH 8
#define DKH 64
#define DFFN 2048
#define NL 2
#define KIDX 5
#define NEGV -1e32f

typedef float f32x4 __attribute__((ext_vector_type(4)));
typedef short bf16x8 __attribute__((ext_vector_type(8)));
typedef unsigned short ushort_t;
typedef __attribute__((address_space(1))) void gvoid;
typedef __attribute__((address_space(3))) void lvoid;

// async global->LDS, 16B per lane; dest is wave-uniform base (+lane*16 by HW)
__device__ __forceinline__ void gload_lds16(const void* g, void* l) {
    __builtin_amdgcn_global_load_lds((gvoid*)(uintptr_t)g, (lvoid*)l, 16, 0, 0);
}

// ---------------- wave (64-lane) reduce helpers ----------------
__device__ __forceinline__ float wmaxf(float v) {
    #pragma unroll
    for (int m = 32; m > 0; m >>= 1) v = fmaxf(v, __shfl_xor(v, m));
    return v;
}
__device__ __forceinline__ float wsumf(float v) {
    #pragma unroll
    for (int m = 32; m > 0; m >>= 1) v += __shfl_xor(v, m);
    return v;
}
__device__ __forceinline__ int wsumi(int v) {
    #pragma unroll
    for (int m = 32; m > 0; m >>= 1) v += __shfl_xor(v, m);
    return v;
}

// ---------------- bf16 split helpers ----------------
__device__ __forceinline__ unsigned int bf16_rne(float x) {
    unsigned int u = __float_as_uint(x);
    return (u + 0x7fffu + ((u >> 16) & 1u)) >> 16;
}
__device__ __forceinline__ void split3_8(const float* xs, unsigned int* hh,
                                         unsigned int* hm, unsigned int* hl) {
    #pragma unroll
    for (int e = 0; e < 8; e++) {
        float x = xs[e];
        unsigned int h0 = bf16_rne(x);
        float r1 = x - __uint_as_float(h0 << 16);
        unsigned int h1 = bf16_rne(r1);
        float r2 = r1 - __uint_as_float(h1 << 16);
        hh[e] = h0; hm[e] = h1; hl[e] = bf16_rne(r2);
    }
}
__device__ __forceinline__ uint4 pack8(const unsigned int* h) {
    return make_uint4(h[0] | (h[1] << 16), h[2] | (h[3] << 16),
                      h[4] | (h[5] << 16), h[6] | (h[7] << 16));
}

__device__ __forceinline__ f32x4 mfma_bf16(bf16x8 a, bf16x8 b, f32x4 c) {
    return __builtin_amdgcn_mfma_f32_16x16x32_bf16(a, b, c, 0, 0, 0);
}

// ---------------- add_pe: x fp32 + y planes ----------------
__global__ void add_pe_new(const float* __restrict__ q, const float* __restrict__ qa,
                           const float* __restrict__ pe, float* __restrict__ x,
                           ushort_t* __restrict__ ypl, size_t yelems, int n8) {
    int i = blockIdx.x * 256 + threadIdx.x;
    if (i >= n8) return;
    size_t base = (size_t)i * 8;
    size_t pb = base & (size_t)(SEQ * DIM - 1);
    float4 a0 = *(const float4*)(q + base), a1 = *(const float4*)(q + base + 4);
    float4 b0 = *(const float4*)(qa + base), b1 = *(const float4*)(qa + base + 4);
    float4 p0 = *(const float4*)(pe + pb), p1 = *(const float4*)(pe + pb + 4);
    float4 x0 = make_float4(a0.x + p0.x, a0.y + p0.y, a0.z + p0.z, a0.w + p0.w);
    float4 x1 = make_float4(a1.x + p1.x, a1.y + p1.y, a1.z + p1.z, a1.w + p1.w);
    *(float4*)(x + base) = x0;
    *(float4*)(x + base + 4) = x1;
    float ys[8] = {b0.x + p0.x, b0.y + p0.y, b0.z + p0.z, b0.w + p0.w,
                   b1.x + p1.x, b1.y + p1.y, b1.z + p1.z, b1.w + p1.w};
    unsigned int hh[8], hm[8], hl[8];
    split3_8(ys, hh, hm, hl);
    *(uint4*)(ypl + base) = pack8(hh);
    *(uint4*)(ypl + yelems + base) = pack8(hm);
    *(uint4*)(ypl + 2 * yelems + base) = pack8(hl);
}

// ---------------- weight pre-split: fp32 -> 3 bf16 planes ----------------
__global__ void split3w(const float* __restrict__ W, ushort_t* __restrict__ out,
                        size_t elems, int n8) {
    int i = blockIdx.x * 256 + threadIdx.x;
    if (i >= n8) return;
    size_t base = (size_t)i * 8;
    float4 a0 = *(const float4*)(W + base), a1 = *(const float4*)(W + base + 4);
    float xs[8] = {a0.x, a0.y, a0.z, a0.w, a1.x, a1.y, a1.z, a1.w};
    unsigned int hh[8], hm[8], hl[8];
    split3_8(xs, hh, hm, hl);
    *(uint4*)(out + base) = pack8(hh);
    *(uint4*)(out + elems + base) = pack8(hm);
    *(uint4*)(out + 2 * elems + base) = pack8(hl);
}

// ---------------- fp32 vector GEMM (selection-critical layer-1 q; exact chains) ----------------
// 512 threads, 128x128 tile, 4x8/thread: per-element k-chain identical to round-1
// (k=0..K-1 sequential fmaf) => bitwise-exact q. (Round-14 PASSED this part; the
// failure was the AV kmax truncation, reverted below.)
template <int RELU>
__global__ __launch_bounds__(512)
void gemm_bt(const float* __restrict__ A, const float* __restrict__ B,
             const float* __restrict__ bias, float* __restrict__ C,
             int M, int N, int K) {
    __shared__ float As[32][132];
    __shared__ float Bs[32][132];
    const int tid = threadIdx.x;
    const int tx = tid & 15, ty = tid >> 4;   // ty 0..31
    const int m0 = blockIdx.y * 128, n0 = blockIdx.x * 128;
    float acc[4][8] = {};
    for (int k0 = 0; k0 < K; k0 += 32) {
        #pragma unroll
        for (int s = tid; s < 1024; s += 512) {
            int r = (s & 15) | ((s >> 7) << 4);   // 2-way-free LDS write banks
            int c4 = (s >> 4) & 7;
            float4 va = *(const float4*)(A + (size_t)(m0 + r) * K + k0 + c4 * 4);
            As[c4 * 4 + 0][r] = va.x; As[c4 * 4 + 1][r] = va.y;
            As[c4 * 4 + 2][r] = va.z; As[c4 * 4 + 3][r] = va.w;
            float4 vb = *(const float4*)(B + (size_t)(n0 + r) * K + k0 + c4 * 4);
            Bs[c4 * 4 + 0][r] = vb.x; Bs[c4 * 4 + 1][r] = vb.y;
            Bs[c4 * 4 + 2][r] = vb.z; Bs[c4 * 4 + 3][r] = vb.w;
        }
        __syncthreads();
        #pragma unroll 8
        for (int kk = 0; kk < 32; kk++) {
            float a[4], b[8];
            *(float4*)&a[0] = *(const float4*)&As[kk][ty * 4];
            *(float4*)&b[0] = *(const float4*)&Bs[kk][tx * 8];
            *(float4*)&b[4] = *(const float4*)&Bs[kk][tx * 8 + 4];
            #pragma unroll
            for (int i = 0; i < 4; i++)
                #pragma unroll
                for (int j = 0; j < 8; j++)
                    acc[i][j] = fmaf(a[i], b[j], acc[i][j]);
        }
        __syncthreads();
    }
    float bv[8];
    *(float4*)&bv[0] = *(const float4*)(bias + n0 + tx * 8);
    *(float4*)&bv[4] = *(const float4*)(bias + n0 + tx * 8 + 4);
    #pragma unroll
    for (int i = 0; i < 4; i++) {
        float out[8];
        #pragma unroll
        for (int j = 0; j < 8; j++) {
            float v = acc[i][j] + bv[j];
            if (RELU) v = fmaxf(v, 0.f);
            out[j] = v;
        }
        float* cp = C + (size_t)(m0 + ty * 4 + i) * N + n0 + tx * 8;
        *(float4*)cp = *(float4*)&out[0];
        *(float4*)(cp + 4) = *(float4*)&out[4];
    }
}

// ---------------- fp32 scores (selection-critical, round-1 arithmetic) ----------------
__global__ __launch_bounds__(256)
void scores128_kernel(const float* __restrict__ q, float* __restrict__ pbuf) {
    const int bh = blockIdx.y, b = bh >> 3, h = bh & 7;
    const int x = blockIdx.x;
    const int it = (x >= 6) ? 3 : (x >= 3) ? 2 : (x >= 1) ? 1 : 0;
    const int jt = x - it * (it + 1) / 2;
    const int m0 = it * 128, n0 = jt * 128;
    __shared__ float Qi[64][132];
    __shared__ float Qj[64][132];
    const float* qbase = q + (size_t)b * SEQ * DIM + h * DKH;
    const int tid = threadIdx.x;
    for (int s = tid; s < 2048; s += 256) {
        int row = (s & 15) | ((s >> 8) << 4);
        int c4 = (s >> 4) & 15;
        float4 vi = *(const float4*)(qbase + (size_t)(m0 + row) * DIM + c4 * 4);
        Qi[c4 * 4 + 0][row] = vi.x; Qi[c4 * 4 + 1][row] = vi.y;
        Qi[c4 * 4 + 2][row] = vi.z; Qi[c4 * 4 + 3][row] = vi.w;
        float4 vj = *(const float4*)(qbase + (size_t)(n0 + row) * DIM + c4 * 4);
        Qj[c4 * 4 + 0][row] = vj.x; Qj[c4 * 4 + 1][row] = vj.y;
        Qj[c4 * 4 + 2][row] = vj.z; Qj[c4 * 4 + 3][row] = vj.w;
    }
    __syncthreads();
    const int tx = tid & 15, ty = tid >> 4;
    float acc[8][8] = {};
    #pragma unroll 4
    for (int d = 0; d < 64; d++) {
        float a[8], bb[8];
        *(float4*)&a[0] = *(const float4*)&Qi[d][ty * 8];
        *(float4*)&a[4] = *(const float4*)&Qi[d][ty * 8 + 4];
        *(float4*)&bb[0] = *(const float4*)&Qj[d][tx * 8];
        *(float4*)&bb[4] = *(const float4*)&Qj[d][tx * 8 + 4];
        #pragma unroll
        for (int i = 0; i < 8; i++)
            #pragma unroll
            for (int j = 0; j < 8; j++)
                acc[i][j] = fmaf(a[i], bb[j], acc[i][j]);
    }
    float* prow = pbuf + ((size_t)bh * SEQ + m0) * SEQ + n0;
    #pragma unroll
    for (int i = 0; i < 8; i++) {
        int gi = m0 + ty * 8 + i;
        #pragma unroll
        for (int jq = 0; jq < 2; jq++) {
            float o[4];
            #pragma unroll
            for (int j = 0; j < 4; j++) {
                int gj = n0 + tx * 8 + jq * 4 + j;
                o[j] = (gj < gi) ? acc[i][jq * 4 + j] * 0.125f : NEGV;
            }
            *(float4*)(prow + (size_t)(ty * 8 + i) * SEQ + tx * 8 + jq * 4) = *(float4*)o;
        }
    }
}

// ---------------- lean NP-plane bf16 GEMM (pre-split operands, async staging) ----------------
template <int RELU, int OUTP, int NP>
__global__ __launch_bounds__(256) void gemm3p(
    const ushort_t* __restrict__ Apl, size_t Aelems, int lda,
    const ushort_t* __restrict__ Bpl, size_t Belems, int ldb,
    const float* __restrict__ bias,
    float* __restrict__ C, ushort_t* __restrict__ Cpl, size_t Celems,
    int ldc, int K) {
    constexpr int BB = NP * 512;               // uint4 idx of B region
    __shared__ uint4 lds[2 * NP * 512];
    const int tid = threadIdx.x, lane = tid & 63, wid = tid >> 6;
    const int wm = wid >> 1, wn = wid & 1;
    const int m0 = blockIdx.y * 128, n0 = blockIdx.x * 128;
    const int lrow = lane & 15, lkof = (lane >> 4) * 8;
    f32x4 acc[4][4] = {};
    for (int k0 = 0; k0 < K; k0 += 32) {
        #pragma unroll
        for (int t = 0; t < 4 * NP; t++) {
            int cc = wid + t * 4;              // 0 .. 16*NP-1
            bool isB = cc >= 8 * NP;
            int c2 = isB ? (cc - 8 * NP) : cc;
            int p = c2 >> 3, fi = c2 & 7;
            const ushort_t* pb = isB ? (Bpl + (size_t)p * Belems) : (Apl + (size_t)p * Aelems);
            int ld = isB ? ldb : lda;
            int r0 = isB ? n0 : m0;
            const ushort_t* src = pb + (size_t)(r0 + fi * 16 + lrow) * ld + k0 + lkof;
            gload_lds16(src, &lds[(isB ? BB : 0) + p * 512 + fi * 64]);
        }
        __syncthreads();
        const bf16x8* ldsb = (const bf16x8*)lds;
        bf16x8 afr[4][NP];
        #pragma unroll
        for (int fm = 0; fm < 4; fm++)
            #pragma unroll
            for (int p = 0; p < NP; p++)
                afr[fm][p] = ldsb[p * 512 + (wm * 4 + fm) * 64 + lane];
        #pragma unroll
        for (int fn = 0; fn < 4; fn++) {
            bf16x8 b0 = ldsb[BB + 0 * 512 + (wn * 4 + fn) * 64 + lane];
            bf16x8 b1 = ldsb[BB + 1 * 512 + (wn * 4 + fn) * 64 + lane];
            bf16x8 b2;
            if constexpr (NP == 3) b2 = ldsb[BB + 2 * 512 + (wn * 4 + fn) * 64 + lane];
            #pragma unroll
            for (int fm = 0; fm < 4; fm++) {
                f32x4 t = acc[fm][fn];
                if constexpr (NP == 3) {
                    t = mfma_bf16(afr[fm][0], b0, t);
                    t = mfma_bf16(afr[fm][1], b0, t);
                    t = mfma_bf16(afr[fm][2], b0, t);
                    t = mfma_bf16(afr[fm][0], b1, t);
                    t = mfma_bf16(afr[fm][1], b1, t);
                    t = mfma_bf16(afr[fm][0], b2, t);
                } else {
                    t = mfma_bf16(afr[fm][0], b0, t);
                    t = mfma_bf16(afr[fm][1], b0, t);
                    t = mfma_bf16(afr[fm][0], b1, t);
                }
                acc[fm][fn] = t;
            }
        }
        __syncthreads();
    }
    #pragma unroll
    for (int fm = 0; fm < 4; fm++) {
        int row0 = m0 + (wm * 4 + fm) * 16 + (lane >> 4) * 4;
        #pragma unroll
        for (int fn = 0; fn < 4; fn++) {
            int col = n0 + (wn * 4 + fn) * 16 + (lane & 15);
            float bv = bias[col];
            f32x4 a = acc[fm][fn];
            #pragma unroll
            for (int r = 0; r < 4; r++) {
                int row = row0 + r;
                float val = a[r] + bv;
                if (RELU) val = fmaxf(val, 0.f);
                if constexpr (OUTP == 0) {
                    C[(size_t)row * ldc + col] = val;
                } else {
                    unsigned int h0 = bf16_rne(val);
                    float r1 = val - __uint_as_float(h0 << 16);
                    unsigned int h1 = bf16_rne(r1);
                    size_t o = (size_t)row * ldc + col;
                    Cpl[o] = (ushort_t)h0;
                    Cpl[Celems + o] = (ushort_t)h1;
                    if constexpr (NP == 3) {
                        float r2 = r1 - __uint_as_float(h1 << 16);
                        Cpl[2 * Celems + o] = (ushort_t)bf16_rne(r2);
                    }
                }
            }
        }
    }
}

// ---------------- AV with NP-plane output (in-kernel split staging) ----------------
// kmax: rb>=1 tiles can stop at their diagonal (weights are exactly 0 beyond it for
// rows >= KIDX, and rb>=1 rows are all >= KIDX). rb==0 holds rows 0..127 INCLUDING
// rows 1..4, whose second softmax keeps exp(0-pm)/Z2 != 0 at ALL 512 columns -> full K.
template <int NP>
__global__ __launch_bounds__(256) void mm6av_pl(const float* __restrict__ pbuf,
                                                const float* __restrict__ vt,
                                                ushort_t* __restrict__ Opl, size_t Oelems) {
    constexpr int BBASE = NP * 512;
    __shared__ uint4 lds[NP * 512 + NP * 256];
    const int tid = threadIdx.x, lane = tid & 63, wid = tid >> 6;
    const int bh = blockIdx.y, b = bh >> 3, h = bh & 7, rb = blockIdx.x;
    const int m0 = rb * 128;
    const float* A = pbuf + (size_t)bh * SEQ * SEQ;
    const float* B = vt + (size_t)bh * DKH * SEQ;
    const int kmax = rb ? (rb + 1) * 128 : SEQ;

    f32x4 acc[2][4] = {};
    for (int k0 = 0; k0 < kmax; k0 += 32) {
        for (int c = tid; c < 12 * 64; c += 256) {
            int fi = c >> 6, lc = c & 63;
            const float* src = (fi < 8)
                ? A + (size_t)(m0 + fi * 16 + (lc & 15)) * SEQ + k0 + (lc >> 4) * 8
                : B + (size_t)((fi - 8) * 16 + (lc & 15)) * SEQ + k0 + (lc >> 4) * 8;
            float4 x0 = *(const float4*)src;
            float4 x1 = *(const float4*)(src + 4);
            float xs[8] = {x0.x, x0.y, x0.z, x0.w, x1.x, x1.y, x1.z, x1.w};
            unsigned int hh[8], hm[8], hl[8];
            split3_8(xs, hh, hm, hl);
            int base, fstride;
            if (fi < 8) { base = fi * 64 + lc; fstride = 512; }
            else { base = BBASE + (fi - 8) * 64 + lc; fstride = 256; }
            lds[base] = pack8(hh);
            lds[base + fstride] = pack8(hm);
            if (NP == 3) lds[base + 2 * fstride] = pack8(hl);
        }
        __syncthreads();
        const bf16x8* ldsb = (const bf16x8*)lds;
        bf16x8 afr[2][NP];
        #pragma unroll
        for (int fm = 0; fm < 2; fm++)
            #pragma unroll
            for (int p = 0; p < NP; p++)
                afr[fm][p] = ldsb[p * 512 + (wid * 2 + fm) * 64 + lane];
        #pragma unroll
        for (int fn = 0; fn < 4; fn++) {
            bf16x8 b0 = ldsb[BBASE + 0 * 256 + fn * 64 + lane];
            bf16x8 b1 = ldsb[BBASE + 1 * 256 + fn * 64 + lane];
            bf16x8 b2;
            if constexpr (NP == 3) b2 = ldsb[BBASE + 2 * 256 + fn * 64 + lane];
            #pragma unroll
            for (int fm = 0; fm < 2; fm++) {
                f32x4 t = acc[fm][fn];
                if constexpr (NP == 3) {
                    t = mfma_bf16(afr[fm][0], b0, t);
                    t = mfma_bf16(afr[fm][1], b0, t);
                    t = mfma_bf16(afr[fm][2], b0, t);
                    t = mfma_bf16(afr[fm][0], b1, t);
                    t = mfma_bf16(afr[fm][1], b1, t);
                    t = mfma_bf16(afr[fm][0], b2, t);
                } else {
                    t = mfma_bf16(afr[fm][0], b0, t);
                    t = mfma_bf16(afr[fm][1], b0, t);
                    t = mfma_bf16(afr[fm][0], b1, t);
                }
                acc[fm][fn] = t;
            }
        }
        __syncthreads();
    }
    #pragma unroll
    for (int fm = 0; fm < 2; fm++) {
        int row0 = m0 + (wid * 2 + fm) * 16 + (lane >> 4) * 4;
        #pragma unroll
        for (int fn = 0; fn < 4; fn++) {
            int col = fn * 16 + (lane & 15);
            f32x4 a = acc[fm][fn];
            #pragma unroll
            for (int r = 0; r < 4; r++) {
                int row = row0 + r;
                float val = (row == 0) ? 0.f : a[r];
                unsigned int h0 = bf16_rne(val);
                float r1 = val - __uint_as_float(h0 << 16);
                unsigned int h1 = bf16_rne(r1);
                size_t o = ((size_t)b * SEQ + row) * DIM + h * DKH + col;
                Opl[o] = (ushort_t)h0;
                Opl[Oelems + o] = (ushort_t)h1;
                if constexpr (NP == 3) {
                    float r2 = r1 - __uint_as_float(h1 << 16);
                    Opl[2 * Oelems + o] = (ushort_t)bf16_rne(r2);
                }
            }
        }
    }
}

// ---------------- V transpose ----------------
__global__ __launch_bounds__(256) void transpose_v_kernel(const float* __restrict__ v,
                                                          float* __restrict__ vt) {
    const int bh = blockIdx.y, jt = blockIdx.x;
    const int b = bh >> 3, h = bh & 7;
    __shared__ float L[64][65];
    const int tid = threadIdx.x;
    for (int s = tid; s < 1024; s += 256) {
        int jj = s >> 4, d4 = s & 15;
        float4 x = *(const float4*)(v + ((size_t)(b * SEQ) + jt * 64 + jj) * DIM + h * DKH + d4 * 4);
        L[jj][d4 * 4 + 0] = x.x; L[jj][d4 * 4 + 1] = x.y;
        L[jj][d4 * 4 + 2] = x.z; L[jj][d4 * 4 + 3] = x.w;
    }
    __syncthreads();
    int d = tid >> 2, jq = tid & 3;
    float* dst = vt + ((size_t)bh * DKH + d) * SEQ + jt * 64 + jq * 16;
    #pragma unroll
    for (int c4 = 0; c4 < 4; c4++) {
        float4 o = make_float4(L[jq * 16 + c4 * 4 + 0][d], L[jq * 16 + c4 * 4 + 1][d],
                               L[jq * 16 + c4 * 4 + 2][d], L[jq * 16 + c4 * 4 + 3][d]);
        *(float4*)(dst + c4 * 4) = o;
    }
}

// ---------------- softmax -> top5 -> second softmax (4 rows per 256-thread block) ----------------
__global__ __launch_bounds__(256)
void softmax_topk_kernel(float* __restrict__ pbuf) {
    const int wid = threadIdx.x >> 6, lane = threadIdx.x & 63;
    const int i = blockIdx.x * 4 + wid;
    const size_t row = (size_t)blockIdx.y * SEQ + i;
    float* p = pbuf + row * SEQ;
    float v[8];
    {
        int j0 = lane * 4;
        if (j0 < i) {
            float4 x0 = *(const float4*)(p + j0);
            v[0] = (j0 + 0 < i) ? x0.x : NEGV;
            v[1] = (j0 + 1 < i) ? x0.y : NEGV;
            v[2] = (j0 + 2 < i) ? x0.z : NEGV;
            v[3] = (j0 + 3 < i) ? x0.w : NEGV;
        } else { v[0] = v[1] = v[2] = v[3] = NEGV; }
        int j1 = 256 + j0;
        if (j1 < i) {
            float4 x1 = *(const float4*)(p + j1);
            v[4] = (j1 + 0 < i) ? x1.x : NEGV;
            v[5] = (j1 + 1 < i) ? x1.y : NEGV;
            v[6] = (j1 + 2 < i) ? x1.z : NEGV;
            v[7] = (j1 + 3 < i) ? x1.w : NEGV;
        } else { v[4] = v[5] = v[6] = v[7] = NEGV; }
    }
    float lm = v[0];
    #pragma unroll
    for (int e = 1; e < 8; e++) lm = fmaxf(lm, v[e]);
    float m1 = wmaxf(lm);
    float ls = 0.f;
    #pragma unroll
    for (int e = 0; e < 8; e++) { v[e] = expf(v[e] - m1); ls += v[e]; }
    float Z = wsumf(ls);
    #pragma unroll
    for (int e = 0; e < 8; e++) v[e] = v[e] / Z;
    float thr = -INFINITY;
    if (i >= KIDX) {
        int remaining = KIDX;
        float cut = INFINITY;
        #pragma unroll 1
        for (int iter = 0; iter < KIDX; iter++) {
            float l2 = -INFINITY;
            #pragma unroll
            for (int e = 0; e < 8; e++) if (v[e] < cut) l2 = fmaxf(l2, v[e]);
            float m2 = wmaxf(l2);
            int lc = 0;
            #pragma unroll
            for (int e = 0; e < 8; e++) if (v[e] == m2) lc++;
            int c = wsumi(lc);
            if (c >= remaining) { thr = m2; break; }
            remaining -= c; cut = m2;
        }
    }
    float lpm = v[0];
    #pragma unroll
    for (int e = 1; e < 8; e++) lpm = fmaxf(lpm, v[e]);
    float pm = wmaxf(lpm);
    float t[8];
    float ls2 = 0.f;
    #pragma unroll
    for (int e = 0; e < 8; e++) {
        bool keep = (i >= KIDX) ? (v[e] >= thr) : true;
        t[e] = keep ? expf(v[e] - pm) : 0.f;
        ls2 += t[e];
    }
    float Z2 = wsumf(ls2);
    #pragma unroll
    for (int e = 0; e < 8; e++) t[e] = t[e] / Z2;
    *(float4*)(p + lane * 4) = make_float4(t[0], t[1], t[2], t[3]);
    *(float4*)(p + 256 + lane * 4) = make_float4(t[4], t[5], t[6], t[7]);
}

// ---------------- dst = LN(x + t)  (EMIT: also write 3 bf16 planes of dst) ----------------
template <int EMIT>
__global__ __launch_bounds__(64)
void add_ln_kernel(const float* __restrict__ x, const float* __restrict__ t,
                   const float* __restrict__ w, const float* __restrict__ b,
                   float* __restrict__ dst, ushort_t* __restrict__ dpl, size_t delems) {
    const size_t row = blockIdx.x;
    const int lane = threadIdx.x;
    const float* xr = x + row * DIM;
    const float* tr = t + row * DIM;
    float v[8];
    {
        float4 a0 = *(const float4*)(xr + lane * 4);
        float4 t0 = *(const float4*)(tr + lane * 4);
        float4 a1 = *(const float4*)(xr + 256 + lane * 4);
        float4 t1 = *(const float4*)(tr + 256 + lane * 4);
        v[0] = a0.x + t0.x; v[1] = a0.y + t0.y; v[2] = a0.z + t0.z; v[3] = a0.w + t0.w;
        v[4] = a1.x + t1.x; v[5] = a1.y + t1.y; v[6] = a1.z + t1.z; v[7] = a1.w + t1.w;
    }
    float ls = 0.f;
    #pragma unroll
    for (int e = 0; e < 8; e++) ls += v[e];
    float mean = wsumf(ls) / (float)DIM;
    float ld = 0.f;
    #pragma unroll
    for (int e = 0; e < 8; e++) { float d = v[e] - mean; ld += d * d; }
    float var = wsumf(ld) / (float)DIM;
    float den = sqrtf(var + 1e-5f);
    float wv[8], bv[8];
    *(float4*)&wv[0] = *(const float4*)(w + lane * 4);
    *(float4*)&wv[4] = *(const float4*)(w + 256 + lane * 4);
    *(float4*)&bv[0] = *(const float4*)(b + lane * 4);
    *(float4*)&bv[4] = *(const float4*)(b + 256 + lane * 4);
    float o[8];
    #pragma unroll
    for (int e = 0; e < 8; e++) o[e] = (v[e] - mean) / den * wv[e] + bv[e];
    float* dr = dst + row * DIM;
    *(float4*)(dr + lane * 4) = make_float4(o[0], o[1], o[2], o[3]);
    *(float4*)(dr + 256 + lane * 4) = make_float4(o[4], o[5], o[6], o[7]);
    if constexpr (EMIT) {
        unsigned int hh[8], hm[8], hl[8];
        split3_8(o, hh, hm, hl);
        size_t base0 = row * DIM + lane * 4;
        size_t base1 = base0 + 256;
        #pragma unroll
        for (int p = 0; p < 3; p++) {
            const unsigned int* hp = (p == 0) ? hh : (p == 1) ? hm : hl;
            *(uint2*)(dpl + p * delems + base0) =
                make_uint2(hp[0] | (hp[1] << 16), hp[2] | (hp[3] << 16));
            *(uint2*)(dpl + p * delems + base1) =
                make_uint2(hp[4] | (hp[5] << 16), hp[6] | (hp[7] << 16));
        }
    }
}

extern "C" void kernel_launch(void* const* d_in, const int* in_sizes, int n_in,
                              void* d_out, int out_size, void* d_ws, size_t ws_size,
                              hipStream_t stream) {
    const float* q_embed = (const float*)d_in[0];
    const float* qa_embed = (const float*)d_in[1];
    const float* pe = (const float*)d_in[2];
    const float* Wk = (const float*)d_in[3];
    const float* bk = (const float*)d_in[4];
    const float* Wv = (const float*)d_in[5];
    const float* bv = (const float*)d_in[6];
    const float* Wo = (const float*)d_in[7];
    const float* bo = (const float*)d_in[8];
    const float* W1 = (const float*)d_in[9];
    const float* b1 = (const float*)d_in[10];
    const float* W2 = (const float*)d_in[11];
    const float* b2 = (const float*)d_in[12];
    const float* ln1w = (const float*)d_in[13];
    const float* ln1b = (const float*)d_in[14];
    const float* ln2w = (const float*)d_in[15];
    const float* ln2b = (const float*)d_in[16];

    float* outx = (float*)d_out;
    const size_t NE = (size_t)BSZ * SEQ * DIM;   // 8388608
    float* pbuf = outx + NE;
    float* ws = (float*)d_ws;
    const int M = BSZ * SEQ;

    // ===================== pre-split planes path (round-8 proven layout) =====================
    float* xbuf = ws;
    float* qbuf = ws + NE;
    float* vbuf = ws + 2 * NE;
    ushort_t* y_pl = (ushort_t*)(ws + 3 * NE);
    ushort_t* x_pl = (ushort_t*)(ws + 4 * NE + NE / 2);
    ushort_t* w_pl = (ushort_t*)(ws + 6 * NE);
    float* vt = ws + 7 * NE;
    ushort_t* o_pl = (ushort_t*)(ws + 8 * NE);
    ushort_t* h1_pl = (ushort_t*)(ws + 7 * NE);   // sequential reuse with vt/o_pl
    ushort_t* wk_pl = (ushort_t*)(ws + 13 * NE);  // Wk[1] planes (layer-2 q only)

    const size_t WVE = (size_t)DIM * DIM;      // 262144
    const size_t W1E = (size_t)DFFN * DIM;     // 1048576
    const size_t LW = 3 * (WVE + WVE + W1E + W1E);

    // layer-2 q via split-6 MFMA requires 13NE floats + 3*WVE ushorts of ws
    const bool q2_mfma = ws_size >= (13 * NE * sizeof(float) + 3 * WVE * sizeof(ushort_t));

    for (int l = 0; l < NL; l++) {
        ushort_t* base = w_pl + (size_t)l * LW;
        split3w<<<(int)(WVE / 8 + 255) / 256, 256, 0, stream>>>(
            Wv + (size_t)l * WVE, base, WVE, (int)(WVE / 8));
        split3w<<<(int)(WVE / 8 + 255) / 256, 256, 0, stream>>>(
            Wo + (size_t)l * WVE, base + 3 * WVE, WVE, (int)(WVE / 8));
        split3w<<<(int)(W1E / 8 + 255) / 256, 256, 0, stream>>>(
            W1 + (size_t)l * W1E, base + 6 * WVE, W1E, (int)(W1E / 8));
        split3w<<<(int)(W1E / 8 + 255) / 256, 256, 0, stream>>>(
            W2 + (size_t)l * W1E, base + 6 * WVE + 3 * W1E, W1E, (int)(W1E / 8));
    }
    if (q2_mfma) {
        split3w<<<(int)(WVE / 8 + 255) / 256, 256, 0, stream>>>(
            Wk + 1 * WVE, wk_pl, WVE, (int)(WVE / 8));
    }

    add_pe_new<<<(int)(NE / 8 + 255) / 256, 256, 0, stream>>>(
        q_embed, qa_embed, pe, xbuf, y_pl, NE, (int)(NE / 8));

    for (int l = 0; l < NL; l++) {
        ushort_t* wb = w_pl + (size_t)l * LW;
        ushort_t* Wv_pl = wb;
        ushort_t* Wo_pl = wb + 3 * WVE;
        ushort_t* W1_pl = wb + 6 * WVE;
        ushort_t* W2_pl = wb + 6 * WVE + 3 * W1E;

        // q projection:
        //   layer 1 (l==0): fp32 exact — structural p-tie exists, any noise flips it.
        //   layer 2 (l==1): split-6 MFMA — proven safe at ~1e-6 score noise.
        if (l == 1 && q2_mfma) {
            gemm3p<0, 0, 3><<<dim3(DIM / 128, M / 128), 256, 0, stream>>>(
                x_pl, NE, DIM, wk_pl, WVE, DIM, bk + (size_t)l * DIM,
                qbuf, nullptr, 0, DIM, DIM);
        } else {
            gemm_bt<0><<<dim3(DIM / 128, M / 128), 512, 0, stream>>>(
                xbuf, Wk + (size_t)l * WVE, bk + (size_t)l * DIM, qbuf, M, DIM, DIM);
        }
        if (l == 0) {
            gemm3p<0, 0, 3><<<dim3(DIM / 128, M / 128), 256, 0, stream>>>(
                y_pl, NE, DIM, Wv_pl, WVE, DIM, bv + (size_t)l * DIM,
                vbuf, nullptr, 0, DIM, DIM);
        } else {
            gemm3p<0, 0, 2><<<dim3(DIM / 128, M / 128), 256, 0, stream>>>(
                y_pl, NE, DIM, Wv_pl, WVE, DIM, bv + (size_t)l * DIM,
                vbuf, nullptr, 0, DIM, DIM);
        }
        transpose_v_kernel<<<dim3(8, BSZ * NH), 256, 0, stream>>>(vbuf, vt);
        scores128_kernel<<<dim3(10, BSZ * NH), 256, 0, stream>>>(qbuf, pbuf);
        softmax_topk_kernel<<<dim3(SEQ / 4, BSZ * NH), 256, 0, stream>>>(pbuf);
        if (l == 0) {
            mm6av_pl<3><<<dim3(4, BSZ * NH), 256, 0, stream>>>(pbuf, vt, o_pl, NE);
            gemm3p<0, 0, 3><<<dim3(DIM / 128, M / 128), 256, 0, stream>>>(
                o_pl, NE, DIM, Wo_pl, WVE, DIM, bo + (size_t)l * DIM,
                qbuf, nullptr, 0, DIM, DIM);
        } else {
            mm6av_pl<2><<<dim3(4, BSZ * NH), 256, 0, stream>>>(pbuf, vt, o_pl, NE);
            gemm3p<0, 0, 2><<<dim3(DIM / 128, M / 128), 256, 0, stream>>>(
                o_pl, NE, DIM, Wo_pl, WVE, DIM, bo + (size_t)l * DIM,
                qbuf, nullptr, 0, DIM, DIM);
        }
        add_ln_kernel<1><<<M, 64, 0, stream>>>(
            xbuf, qbuf, ln1w + (size_t)l * DIM, ln1b + (size_t)l * DIM,
            xbuf, x_pl, NE);
        if (l == 0) {
            gemm3p<1, 1, 3><<<dim3(DFFN / 128, M / 128), 256, 0, stream>>>(
                x_pl, NE, DIM, W1_pl, W1E, DIM, b1 + (size_t)l * DFFN,
                nullptr, h1_pl, (size_t)M * DFFN, DFFN, DIM);
            gemm3p<0, 0, 3><<<dim3(DIM / 128, M / 128), 256, 0, stream>>>(
                h1_pl, (size_t)M * DFFN, DFFN, W2_pl, W1E, DFFN, b2 + (size_t)l * DIM,
                vbuf, nullptr, 0, DIM, DFFN);
        } else {
            gemm3p<1, 1, 2><<<dim3(DFFN / 128, M / 128), 256, 0, stream>>>(
                x_pl, NE, DIM, W1_pl, W1E, DIM, b1 + (size_t)l * DFFN,
                nullptr, h1_pl, (size_t)M * DFFN, DFFN, DIM);
            gemm3p<0, 0, 2><<<dim3(DIM / 128, M / 128), 256, 0, stream>>>(
                h1_pl, (size_t)M * DFFN, DFFN, W2_pl, W1E, DFFN, b2 + (size_t)l * DIM,
                vbuf, nullptr, 0, DIM, DFFN);
        }
        // x = LN(x + ff); after layer 0 also emit x planes for layer-2's q-projection
        if (l == NL - 1) {
            add_ln_kernel<0><<<M, 64, 0, stream>>>(
                xbuf, vbuf, ln2w + (size_t)l * DIM, ln2b + (size_t)l * DIM,
                outx, nullptr, 0);
        } else if (q2_mfma) {
            add_ln_kernel<1><<<M, 64, 0, stream>>>(
                xbuf, vbuf, ln2w + (size_t)l * DIM, ln2b + (size_t)l * DIM,
                xbuf, x_pl, NE);
        } else {
            add_ln_kernel<0><<<M, 64, 0, stream>>>(
                xbuf, vbuf, ln2w + (size_t)l * DIM, ln2b + (size_t)l * DIM,
                xbuf, nullptr, 0);
        }
    }
}

// Round 16
// 1951.159 us; speedup vs baseline: 1.0023x; 1.0008x over previous
//
#include <hip/hip_runtime.h>
#include <hip/hip_bf16.h>
#include <math.h>

#define BSZ 32
#define SEQ 512
#define DIM 512
#define NH 8
#define DKH 64
#define DFFN 2048
#define NL 2
#define KIDX 5
#define NEGV -1e32f

typedef float f32x4 __attribute__((ext_vector_type(4)));
typedef short bf16x8 __attribute__((ext_vector_type(8)));
typedef unsigned short ushort_t;
typedef __attribute__((address_space(1))) void gvoid;
typedef __attribute__((address_space(3))) void lvoid;

// async global->LDS, 16B per lane; dest is wave-uniform base (+lane*16 by HW)
__device__ __forceinline__ void gload_lds16(const void* g, void* l) {
    __builtin_amdgcn_global_load_lds((gvoid*)(uintptr_t)g, (lvoid*)l, 16, 0, 0);
}

// ---------------- wave (64-lane) reduce helpers ----------------
__device__ __forceinline__ float wmaxf(float v) {
    #pragma unroll
    for (int m = 32; m > 0; m >>= 1) v = fmaxf(v, __shfl_xor(v, m));
    return v;
}
__device__ __forceinline__ float wsumf(float v) {
    #pragma unroll
    for (int m = 32; m > 0; m >>= 1) v += __shfl_xor(v, m);
    return v;
}
__device__ __forceinline__ int wsumi(int v) {
    #pragma unroll
    for (int m = 32; m > 0; m >>= 1) v += __shfl_xor(v, m);
    return v;
}

// ---------------- bf16 split helpers ----------------
__device__ __forceinline__ unsigned int bf16_rne(float x) {
    unsigned int u = __float_as_uint(x);
    return (u + 0x7fffu + ((u >> 16) & 1u)) >> 16;
}
__device__ __forceinline__ void split3_8(const float* xs, unsigned int* hh,
                                         unsigned int* hm, unsigned int* hl) {
    #pragma unroll
    for (int e = 0; e < 8; e++) {
        float x = xs[e];
        unsigned int h0 = bf16_rne(x);
        float r1 = x - __uint_as_float(h0 << 16);
        unsigned int h1 = bf16_rne(r1);
        float r2 = r1 - __uint_as_float(h1 << 16);
        hh[e] = h0; hm[e] = h1; hl[e] = bf16_rne(r2);
    }
}
__device__ __forceinline__ uint4 pack8(const unsigned int* h) {
    return make_uint4(h[0] | (h[1] << 16), h[2] | (h[3] << 16),
                      h[4] | (h[5] << 16), h[6] | (h[7] << 16));
}

__device__ __forceinline__ f32x4 mfma_bf16(bf16x8 a, bf16x8 b, f32x4 c) {
    return __builtin_amdgcn_mfma_f32_16x16x32_bf16(a, b, c, 0, 0, 0);
}

// ---------------- add_pe: x fp32 + y planes ----------------
__global__ void add_pe_new(const float* __restrict__ q, const float* __restrict__ qa,
                           const float* __restrict__ pe, float* __restrict__ x,
                           ushort_t* __restrict__ ypl, size_t yelems, int n8) {
    int i = blockIdx.x * 256 + threadIdx.x;
    if (i >= n8) return;
    size_t base = (size_t)i * 8;
    size_t pb = base & (size_t)(SEQ * DIM - 1);
    float4 a0 = *(const float4*)(q + base), a1 = *(const float4*)(q + base + 4);
    float4 b0 = *(const float4*)(qa + base), b1 = *(const float4*)(qa + base + 4);
    float4 p0 = *(const float4*)(pe + pb), p1 = *(const float4*)(pe + pb + 4);
    float4 x0 = make_float4(a0.x + p0.x, a0.y + p0.y, a0.z + p0.z, a0.w + p0.w);
    float4 x1 = make_float4(a1.x + p1.x, a1.y + p1.y, a1.z + p1.z, a1.w + p1.w);
    *(float4*)(x + base) = x0;
    *(float4*)(x + base + 4) = x1;
    float ys[8] = {b0.x + p0.x, b0.y + p0.y, b0.z + p0.z, b0.w + p0.w,
                   b1.x + p1.x, b1.y + p1.y, b1.z + p1.z, b1.w + p1.w};
    unsigned int hh[8], hm[8], hl[8];
    split3_8(ys, hh, hm, hl);
    *(uint4*)(ypl + base) = pack8(hh);
    *(uint4*)(ypl + yelems + base) = pack8(hm);
    *(uint4*)(ypl + 2 * yelems + base) = pack8(hl);
}

// ---------------- weight pre-split: fp32 -> 3 bf16 planes ----------------
__global__ void split3w(const float* __restrict__ W, ushort_t* __restrict__ out,
                        size_t elems, int n8) {
    int i = blockIdx.x * 256 + threadIdx.x;
    if (i >= n8) return;
    size_t base = (size_t)i * 8;
    float4 a0 = *(const float4*)(W + base), a1 = *(const float4*)(W + base + 4);
    float xs[8] = {a0.x, a0.y, a0.z, a0.w, a1.x, a1.y, a1.z, a1.w};
    unsigned int hh[8], hm[8], hl[8];
    split3_8(xs, hh, hm, hl);
    *(uint4*)(out + base) = pack8(hh);
    *(uint4*)(out + elems + base) = pack8(hm);
    *(uint4*)(out + 2 * elems + base) = pack8(hl);
}

// ---------------- fp32 vector GEMM (selection-critical layer-1 q; exact chains) ----------------
// 512 threads, 128x128 tile, 4x8/thread: per-element k-chain identical to round-1
// (k=0..K-1 sequential fmaf) => bitwise-exact q. (Round-14 PASSED this part; the
// failure was the AV kmax truncation, reverted below.)
template <int RELU>
__global__ __launch_bounds__(512)
void gemm_bt(const float* __restrict__ A, const float* __restrict__ B,
             const float* __restrict__ bias, float* __restrict__ C,
             int M, int N, int K) {
    __shared__ float As[32][132];
    __shared__ float Bs[32][132];
    const int tid = threadIdx.x;
    const int tx = tid & 15, ty = tid >> 4;   // ty 0..31
    const int m0 = blockIdx.y * 128, n0 = blockIdx.x * 128;
    float acc[4][8] = {};
    for (int k0 = 0; k0 < K; k0 += 32) {
        #pragma unroll
        for (int s = tid; s < 1024; s += 512) {
            int r = (s & 15) | ((s >> 7) << 4);   // 2-way-free LDS write banks
            int c4 = (s >> 4) & 7;
            float4 va = *(const float4*)(A + (size_t)(m0 + r) * K + k0 + c4 * 4);
            As[c4 * 4 + 0][r] = va.x; As[c4 * 4 + 1][r] = va.y;
            As[c4 * 4 + 2][r] = va.z; As[c4 * 4 + 3][r] = va.w;
            float4 vb = *(const float4*)(B + (size_t)(n0 + r) * K + k0 + c4 * 4);
            Bs[c4 * 4 + 0][r] = vb.x; Bs[c4 * 4 + 1][r] = vb.y;
            Bs[c4 * 4 + 2][r] = vb.z; Bs[c4 * 4 + 3][r] = vb.w;
        }
        __syncthreads();
        #pragma unroll 8
        for (int kk = 0; kk < 32; kk++) {
            float a[4], b[8];
            *(float4*)&a[0] = *(const float4*)&As[kk][ty * 4];
            *(float4*)&b[0] = *(const float4*)&Bs[kk][tx * 8];
            *(float4*)&b[4] = *(const float4*)&Bs[kk][tx * 8 + 4];
            #pragma unroll
            for (int i = 0; i < 4; i++)
                #pragma unroll
                for (int j = 0; j < 8; j++)
                    acc[i][j] = fmaf(a[i], b[j], acc[i][j]);
        }
        __syncthreads();
    }
    float bv[8];
    *(float4*)&bv[0] = *(const float4*)(bias + n0 + tx * 8);
    *(float4*)&bv[4] = *(const float4*)(bias + n0 + tx * 8 + 4);
    #pragma unroll
    for (int i = 0; i < 4; i++) {
        float out[8];
        #pragma unroll
        for (int j = 0; j < 8; j++) {
            float v = acc[i][j] + bv[j];
            if (RELU) v = fmaxf(v, 0.f);
            out[j] = v;
        }
        float* cp = C + (size_t)(m0 + ty * 4 + i) * N + n0 + tx * 8;
        *(float4*)cp = *(float4*)&out[0];
        *(float4*)(cp + 4) = *(float4*)&out[4];
    }
}

// ---------------- fp32 scores (selection-critical, round-1 arithmetic) ----------------
__global__ __launch_bounds__(256)
void scores128_kernel(const float* __restrict__ q, float* __restrict__ pbuf) {
    const int bh = blockIdx.y, b = bh >> 3, h = bh & 7;
    const int x = blockIdx.x;
    const int it = (x >= 6) ? 3 : (x >= 3) ? 2 : (x >= 1) ? 1 : 0;
    const int jt = x - it * (it + 1) / 2;
    const int m0 = it * 128, n0 = jt * 128;
    __shared__ float Qi[64][132];
    __shared__ float Qj[64][132];
    const float* qbase = q + (size_t)b * SEQ * DIM + h * DKH;
    const int tid = threadIdx.x;
    for (int s = tid; s < 2048; s += 256) {
        int row = (s & 15) | ((s >> 8) << 4);
        int c4 = (s >> 4) & 15;
        float4 vi = *(const float4*)(qbase + (size_t)(m0 + row) * DIM + c4 * 4);
        Qi[c4 * 4 + 0][row] = vi.x; Qi[c4 * 4 + 1][row] = vi.y;
        Qi[c4 * 4 + 2][row] = vi.z; Qi[c4 * 4 + 3][row] = vi.w;
        float4 vj = *(const float4*)(qbase + (size_t)(n0 + row) * DIM + c4 * 4);
        Qj[c4 * 4 + 0][row] = vj.x; Qj[c4 * 4 + 1][row] = vj.y;
        Qj[c4 * 4 + 2][row] = vj.z; Qj[c4 * 4 + 3][row] = vj.w;
    }
    __syncthreads();
    const int tx = tid & 15, ty = tid >> 4;
    float acc[8][8] = {};
    #pragma unroll 4
    for (int d = 0; d < 64; d++) {
        float a[8], bb[8];
        *(float4*)&a[0] = *(const float4*)&Qi[d][ty * 8];
        *(float4*)&a[4] = *(const float4*)&Qi[d][ty * 8 + 4];
        *(float4*)&bb[0] = *(const float4*)&Qj[d][tx * 8];
        *(float4*)&bb[4] = *(const float4*)&Qj[d][tx * 8 + 4];
        #pragma unroll
        for (int i = 0; i < 8; i++)
            #pragma unroll
            for (int j = 0; j < 8; j++)
                acc[i][j] = fmaf(a[i], bb[j], acc[i][j]);
    }
    float* prow = pbuf + ((size_t)bh * SEQ + m0) * SEQ + n0;
    #pragma unroll
    for (int i = 0; i < 8; i++) {
        int gi = m0 + ty * 8 + i;
        #pragma unroll
        for (int jq = 0; jq < 2; jq++) {
            float o[4];
            #pragma unroll
            for (int j = 0; j < 4; j++) {
                int gj = n0 + tx * 8 + jq * 4 + j;
                o[j] = (gj < gi) ? acc[i][jq * 4 + j] * 0.125f : NEGV;
            }
            *(float4*)(prow + (size_t)(ty * 8 + i) * SEQ + tx * 8 + jq * 4) = *(float4*)o;
        }
    }
}

// ---------------- lean NP-plane bf16 GEMM (pre-split operands, async staging) ----------------
template <int RELU, int OUTP, int NP>
__global__ __launch_bounds__(256) void gemm3p(
    const ushort_t* __restrict__ Apl, size_t Aelems, int lda,
    const ushort_t* __restrict__ Bpl, size_t Belems, int ldb,
    const float* __restrict__ bias,
    float* __restrict__ C, ushort_t* __restrict__ Cpl, size_t Celems,
    int ldc, int K) {
    constexpr int BB = NP * 512;               // uint4 idx of B region
    __shared__ uint4 lds[2 * NP * 512];
    const int tid = threadIdx.x, lane = tid & 63, wid = tid >> 6;
    const int wm = wid >> 1, wn = wid & 1;
    const int m0 = blockIdx.y * 128, n0 = blockIdx.x * 128;
    const int lrow = lane & 15, lkof = (lane >> 4) * 8;
    f32x4 acc[4][4] = {};
    for (int k0 = 0; k0 < K; k0 += 32) {
        #pragma unroll
        for (int t = 0; t < 4 * NP; t++) {
            int cc = wid + t * 4;              // 0 .. 16*NP-1
            bool isB = cc >= 8 * NP;
            int c2 = isB ? (cc - 8 * NP) : cc;
            int p = c2 >> 3, fi = c2 & 7;
            const ushort_t* pb = isB ? (Bpl + (size_t)p * Belems) : (Apl + (size_t)p * Aelems);
            int ld = isB ? ldb : lda;
            int r0 = isB ? n0 : m0;
            const ushort_t* src = pb + (size_t)(r0 + fi * 16 + lrow) * ld + k0 + lkof;
            gload_lds16(src, &lds[(isB ? BB : 0) + p * 512 + fi * 64]);
        }
        __syncthreads();
        const bf16x8* ldsb = (const bf16x8*)lds;
        bf16x8 afr[4][NP];
        #pragma unroll
        for (int fm = 0; fm < 4; fm++)
            #pragma unroll
            for (int p = 0; p < NP; p++)
                afr[fm][p] = ldsb[p * 512 + (wm * 4 + fm) * 64 + lane];
        #pragma unroll
        for (int fn = 0; fn < 4; fn++) {
            bf16x8 b0 = ldsb[BB + 0 * 512 + (wn * 4 + fn) * 64 + lane];
            bf16x8 b1 = ldsb[BB + 1 * 512 + (wn * 4 + fn) * 64 + lane];
            bf16x8 b2;
            if constexpr (NP == 3) b2 = ldsb[BB + 2 * 512 + (wn * 4 + fn) * 64 + lane];
            #pragma unroll
            for (int fm = 0; fm < 4; fm++) {
                f32x4 t = acc[fm][fn];
                if constexpr (NP == 3) {
                    t = mfma_bf16(afr[fm][0], b0, t);
                    t = mfma_bf16(afr[fm][1], b0, t);
                    t = mfma_bf16(afr[fm][2], b0, t);
                    t = mfma_bf16(afr[fm][0], b1, t);
                    t = mfma_bf16(afr[fm][1], b1, t);
                    t = mfma_bf16(afr[fm][0], b2, t);
                } else {
                    t = mfma_bf16(afr[fm][0], b0, t);
                    t = mfma_bf16(afr[fm][1], b0, t);
                    t = mfma_bf16(afr[fm][0], b1, t);
                }
                acc[fm][fn] = t;
            }
        }
        __syncthreads();
    }
    #pragma unroll
    for (int fm = 0; fm < 4; fm++) {
        int row0 = m0 + (wm * 4 + fm) * 16 + (lane >> 4) * 4;
        #pragma unroll
        for (int fn = 0; fn < 4; fn++) {
            int col = n0 + (wn * 4 + fn) * 16 + (lane & 15);
            float bv = bias[col];
            f32x4 a = acc[fm][fn];
            #pragma unroll
            for (int r = 0; r < 4; r++) {
                int row = row0 + r;
                float val = a[r] + bv;
                if (RELU) val = fmaxf(val, 0.f);
                if constexpr (OUTP == 0) {
                    C[(size_t)row * ldc + col] = val;
                } else {
                    unsigned int h0 = bf16_rne(val);
                    float r1 = val - __uint_as_float(h0 << 16);
                    unsigned int h1 = bf16_rne(r1);
                    size_t o = (size_t)row * ldc + col;
                    Cpl[o] = (ushort_t)h0;
                    Cpl[Celems + o] = (ushort_t)h1;
                    if constexpr (NP == 3) {
                        float r2 = r1 - __uint_as_float(h1 << 16);
                        Cpl[2 * Celems + o] = (ushort_t)bf16_rne(r2);
                    }
                }
            }
        }
    }
}

// ---------------- AV with NP-plane output (in-kernel split staging) ----------------
// kmax: rb>=1 tiles can stop at their diagonal (weights are exactly 0 beyond it for
// rows >= KIDX, and rb>=1 rows are all >= KIDX). rb==0 holds rows 0..127 INCLUDING
// rows 1..4, whose second softmax keeps exp(0-pm)/Z2 != 0 at ALL 512 columns -> full K.
template <int NP>
__global__ __launch_bounds__(256) void mm6av_pl(const float* __restrict__ pbuf,
                                                const float* __restrict__ vt,
                                                ushort_t* __restrict__ Opl, size_t Oelems) {
    constexpr int BBASE = NP * 512;
    __shared__ uint4 lds[NP * 512 + NP * 256];
    const int tid = threadIdx.x, lane = tid & 63, wid = tid >> 6;
    const int bh = blockIdx.y, b = bh >> 3, h = bh & 7, rb = blockIdx.x;
    const int m0 = rb * 128;
    const float* A = pbuf + (size_t)bh * SEQ * SEQ;
    const float* B = vt + (size_t)bh * DKH * SEQ;
    const int kmax = rb ? (rb + 1) * 128 : SEQ;

    f32x4 acc[2][4] = {};
    for (int k0 = 0; k0 < kmax; k0 += 32) {
        for (int c = tid; c < 12 * 64; c += 256) {
            int fi = c >> 6, lc = c & 63;
            const float* src = (fi < 8)
                ? A + (size_t)(m0 + fi * 16 + (lc & 15)) * SEQ + k0 + (lc >> 4) * 8
                : B + (size_t)((fi - 8) * 16 + (lc & 15)) * SEQ + k0 + (lc >> 4) * 8;
            float4 x0 = *(const float4*)src;
            float4 x1 = *(const float4*)(src + 4);
            float xs[8] = {x0.x, x0.y, x0.z, x0.w, x1.x, x1.y, x1.z, x1.w};
            unsigned int hh[8], hm[8], hl[8];
            split3_8(xs, hh, hm, hl);
            int base, fstride;
            if (fi < 8) { base = fi * 64 + lc; fstride = 512; }
            else { base = BBASE + (fi - 8) * 64 + lc; fstride = 256; }
            lds[base] = pack8(hh);
            lds[base + fstride] = pack8(hm);
            if (NP == 3) lds[base + 2 * fstride] = pack8(hl);
        }
        __syncthreads();
        const bf16x8* ldsb = (const bf16x8*)lds;
        bf16x8 afr[2][NP];
        #pragma unroll
        for (int fm = 0; fm < 2; fm++)
            #pragma unroll
            for (int p = 0; p < NP; p++)
                afr[fm][p] = ldsb[p * 512 + (wid * 2 + fm) * 64 + lane];
        #pragma unroll
        for (int fn = 0; fn < 4; fn++) {
            bf16x8 b0 = ldsb[BBASE + 0 * 256 + fn * 64 + lane];
            bf16x8 b1 = ldsb[BBASE + 1 * 256 + fn * 64 + lane];
            bf16x8 b2;
            if constexpr (NP == 3) b2 = ldsb[BBASE + 2 * 256 + fn * 64 + lane];
            #pragma unroll
            for (int fm = 0; fm < 2; fm++) {
                f32x4 t = acc[fm][fn];
                if constexpr (NP == 3) {
                    t = mfma_bf16(afr[fm][0], b0, t);
                    t = mfma_bf16(afr[fm][1], b0, t);
                    t = mfma_bf16(afr[fm][2], b0, t);
                    t = mfma_bf16(afr[fm][0], b1, t);
                    t = mfma_bf16(afr[fm][1], b1, t);
                    t = mfma_bf16(afr[fm][0], b2, t);
                } else {
                    t = mfma_bf16(afr[fm][0], b0, t);
                    t = mfma_bf16(afr[fm][1], b0, t);
                    t = mfma_bf16(afr[fm][0], b1, t);
                }
                acc[fm][fn] = t;
            }
        }
        __syncthreads();
    }
    #pragma unroll
    for (int fm = 0; fm < 2; fm++) {
        int row0 = m0 + (wid * 2 + fm) * 16 + (lane >> 4) * 4;
        #pragma unroll
        for (int fn = 0; fn < 4; fn++) {
            int col = fn * 16 + (lane & 15);
            f32x4 a = acc[fm][fn];
            #pragma unroll
            for (int r = 0; r < 4; r++) {
                int row = row0 + r;
                float val = (row == 0) ? 0.f : a[r];
                unsigned int h0 = bf16_rne(val);
                float r1 = val - __uint_as_float(h0 << 16);
                unsigned int h1 = bf16_rne(r1);
                size_t o = ((size_t)b * SEQ + row) * DIM + h * DKH + col;
                Opl[o] = (ushort_t)h0;
                Opl[Oelems + o] = (ushort_t)h1;
                if constexpr (NP == 3) {
                    float r2 = r1 - __uint_as_float(h1 << 16);
                    Opl[2 * Oelems + o] = (ushort_t)bf16_rne(r2);
                }
            }
        }
    }
}

// ---------------- V transpose ----------------
__global__ __launch_bounds__(256) void transpose_v_kernel(const float* __restrict__ v,
                                                          float* __restrict__ vt) {
    const int bh = blockIdx.y, jt = blockIdx.x;
    const int b = bh >> 3, h = bh & 7;
    __shared__ float L[64][65];
    const int tid = threadIdx.x;
    for (int s = tid; s < 1024; s += 256) {
        int jj = s >> 4, d4 = s & 15;
        float4 x = *(const float4*)(v + ((size_t)(b * SEQ) + jt * 64 + jj) * DIM + h * DKH + d4 * 4);
        L[jj][d4 * 4 + 0] = x.x; L[jj][d4 * 4 + 1] = x.y;
        L[jj][d4 * 4 + 2] = x.z; L[jj][d4 * 4 + 3] = x.w;
    }
    __syncthreads();
    int d = tid >> 2, jq = tid & 3;
    float* dst = vt + ((size_t)bh * DKH + d) * SEQ + jt * 64 + jq * 16;
    #pragma unroll
    for (int c4 = 0; c4 < 4; c4++) {
        float4 o = make_float4(L[jq * 16 + c4 * 4 + 0][d], L[jq * 16 + c4 * 4 + 1][d],
                               L[jq * 16 + c4 * 4 + 2][d], L[jq * 16 + c4 * 4 + 3][d]);
        *(float4*)(dst + c4 * 4) = o;
    }
}

// ---------------- softmax -> top5 -> second softmax (4 rows per 256-thread block) ----------------
__global__ __launch_bounds__(256)
void softmax_topk_kernel(float* __restrict__ pbuf) {
    const int wid = threadIdx.x >> 6, lane = threadIdx.x & 63;
    const int i = blockIdx.x * 4 + wid;
    const size_t row = (size_t)blockIdx.y * SEQ + i;
    float* p = pbuf + row * SEQ;
    float v[8];
    {
        int j0 = lane * 4;
        if (j0 < i) {
            float4 x0 = *(const float4*)(p + j0);
            v[0] = (j0 + 0 < i) ? x0.x : NEGV;
            v[1] = (j0 + 1 < i) ? x0.y : NEGV;
            v[2] = (j0 + 2 < i) ? x0.z : NEGV;
            v[3] = (j0 + 3 < i) ? x0.w : NEGV;
        } else { v[0] = v[1] = v[2] = v[3] = NEGV; }
        int j1 = 256 + j0;
        if (j1 < i) {
            float4 x1 = *(const float4*)(p + j1);
            v[4] = (j1 + 0 < i) ? x1.x : NEGV;
            v[5] = (j1 + 1 < i) ? x1.y : NEGV;
            v[6] = (j1 + 2 < i) ? x1.z : NEGV;
            v[7] = (j1 + 3 < i) ? x1.w : NEGV;
        } else { v[4] = v[5] = v[6] = v[7] = NEGV; }
    }
    float lm = v[0];
    #pragma unroll
    for (int e = 1; e < 8; e++) lm = fmaxf(lm, v[e]);
    float m1 = wmaxf(lm);
    float ls = 0.f;
    #pragma unroll
    for (int e = 0; e < 8; e++) { v[e] = expf(v[e] - m1); ls += v[e]; }
    float Z = wsumf(ls);
    #pragma unroll
    for (int e = 0; e < 8; e++) v[e] = v[e] / Z;
    float thr = -INFINITY;
    if (i >= KIDX) {
        int remaining = KIDX;
        float cut = INFINITY;
        #pragma unroll 1
        for (int iter = 0; iter < KIDX; iter++) {
            float l2 = -INFINITY;
            #pragma unroll
            for (int e = 0; e < 8; e++) if (v[e] < cut) l2 = fmaxf(l2, v[e]);
            float m2 = wmaxf(l2);
            int lc = 0;
            #pragma unroll
            for (int e = 0; e < 8; e++) if (v[e] == m2) lc++;
            int c = wsumi(lc);
            if (c >= remaining) { thr = m2; break; }
            remaining -= c; cut = m2;
        }
    }
    float lpm = v[0];
    #pragma unroll
    for (int e = 1; e < 8; e++) lpm = fmaxf(lpm, v[e]);
    float pm = wmaxf(lpm);
    float t[8];
    float ls2 = 0.f;
    #pragma unroll
    for (int e = 0; e < 8; e++) {
        bool keep = (i >= KIDX) ? (v[e] >= thr) : true;
        t[e] = keep ? expf(v[e] - pm) : 0.f;
        ls2 += t[e];
    }
    float Z2 = wsumf(ls2);
    #pragma unroll
    for (int e = 0; e < 8; e++) t[e] = t[e] / Z2;
    *(float4*)(p + lane * 4) = make_float4(t[0], t[1], t[2], t[3]);
    *(float4*)(p + 256 + lane * 4) = make_float4(t[4], t[5], t[6], t[7]);
}

// ---------------- dst = LN(x + t)  (EMIT: also write 3 bf16 planes of dst) ----------------
template <int EMIT>
__global__ __launch_bounds__(64)
void add_ln_kernel(const float* __restrict__ x, const float* __restrict__ t,
                   const float* __restrict__ w, const float* __restrict__ b,
                   float* __restrict__ dst, ushort_t* __restrict__ dpl, size_t delems) {
    const size_t row = blockIdx.x;
    const int lane = threadIdx.x;
    const float* xr = x + row * DIM;
    const float* tr = t + row * DIM;
    float v[8];
    {
        float4 a0 = *(const float4*)(xr + lane * 4);
        float4 t0 = *(const float4*)(tr + lane * 4);
        float4 a1 = *(const float4*)(xr + 256 + lane * 4);
        float4 t1 = *(const float4*)(tr + 256 + lane * 4);
        v[0] = a0.x + t0.x; v[1] = a0.y + t0.y; v[2] = a0.z + t0.z; v[3] = a0.w + t0.w;
        v[4] = a1.x + t1.x; v[5] = a1.y + t1.y; v[6] = a1.z + t1.z; v[7] = a1.w + t1.w;
    }
    float ls = 0.f;
    #pragma unroll
    for (int e = 0; e < 8; e++) ls += v[e];
    float mean = wsumf(ls) / (float)DIM;
    float ld = 0.f;
    #pragma unroll
    for (int e = 0; e < 8; e++) { float d = v[e] - mean; ld += d * d; }
    float var = wsumf(ld) / (float)DIM;
    float den = sqrtf(var + 1e-5f);
    float wv[8], bv[8];
    *(float4*)&wv[0] = *(const float4*)(w + lane * 4);
    *(float4*)&wv[4] = *(const float4*)(w + 256 + lane * 4);
    *(float4*)&bv[0] = *(const float4*)(b + lane * 4);
    *(float4*)&bv[4] = *(const float4*)(b + 256 + lane * 4);
    float o[8];
    #pragma unroll
    for (int e = 0; e < 8; e++) o[e] = (v[e] - mean) / den * wv[e] + bv[e];
    float* dr = dst + row * DIM;
    *(float4*)(dr + lane * 4) = make_float4(o[0], o[1], o[2], o[3]);
    *(float4*)(dr + 256 + lane * 4) = make_float4(o[4], o[5], o[6], o[7]);
    if constexpr (EMIT) {
        unsigned int hh[8], hm[8], hl[8];
        split3_8(o, hh, hm, hl);
        size_t base0 = row * DIM + lane * 4;
        size_t base1 = base0 + 256;
        #pragma unroll
        for (int p = 0; p < 3; p++) {
            const unsigned int* hp = (p == 0) ? hh : (p == 1) ? hm : hl;
            *(uint2*)(dpl + p * delems + base0) =
                make_uint2(hp[0] | (hp[1] << 16), hp[2] | (hp[3] << 16));
            *(uint2*)(dpl + p * delems + base1) =
                make_uint2(hp[4] | (hp[5] << 16), hp[6] | (hp[7] << 16));
        }
    }
}

extern "C" void kernel_launch(void* const* d_in, const int* in_sizes, int n_in,
                              void* d_out, int out_size, void* d_ws, size_t ws_size,
                              hipStream_t stream) {
    const float* q_embed = (const float*)d_in[0];
    const float* qa_embed = (const float*)d_in[1];
    const float* pe = (const float*)d_in[2];
    const float* Wk = (const float*)d_in[3];
    const float* bk = (const float*)d_in[4];
    const float* Wv = (const float*)d_in[5];
    const float* bv = (const float*)d_in[6];
    const float* Wo = (const float*)d_in[7];
    const float* bo = (const float*)d_in[8];
    const float* W1 = (const float*)d_in[9];
    const float* b1 = (const float*)d_in[10];
    const float* W2 = (const float*)d_in[11];
    const float* b2 = (const float*)d_in[12];
    const float* ln1w = (const float*)d_in[13];
    const float* ln1b = (const float*)d_in[14];
    const float* ln2w = (const float*)d_in[15];
    const float* ln2b = (const float*)d_in[16];

    float* outx = (float*)d_out;
    const size_t NE = (size_t)BSZ * SEQ * DIM;   // 8388608
    float* pbuf = outx + NE;
    float* ws = (float*)d_ws;
    const int M = BSZ * SEQ;

    // ===================== pre-split planes path (round-8 proven layout) =====================
    float* xbuf = ws;
    float* qbuf = ws + NE;
    float* vbuf = ws + 2 * NE;
    ushort_t* y_pl = (ushort_t*)(ws + 3 * NE);
    ushort_t* x_pl = (ushort_t*)(ws + 4 * NE + NE / 2);
    ushort_t* w_pl = (ushort_t*)(ws + 6 * NE);
    float* vt = ws + 7 * NE;
    ushort_t* o_pl = (ushort_t*)(ws + 8 * NE);
    ushort_t* h1_pl = (ushort_t*)(ws + 7 * NE);   // sequential reuse with vt/o_pl
    ushort_t* wk_pl = (ushort_t*)(ws + 13 * NE);  // Wk[1] planes (layer-2 q only)

    const size_t WVE = (size_t)DIM * DIM;      // 262144
    const size_t W1E = (size_t)DFFN * DIM;     // 1048576
    const size_t LW = 3 * (WVE + WVE + W1E + W1E);

    // layer-2 q via split-6 MFMA requires 13NE floats + 3*WVE ushorts of ws
    const bool q2_mfma = ws_size >= (13 * NE * sizeof(float) + 3 * WVE * sizeof(ushort_t));

    for (int l = 0; l < NL; l++) {
        ushort_t* base = w_pl + (size_t)l * LW;
        split3w<<<(int)(WVE / 8 + 255) / 256, 256, 0, stream>>>(
            Wv + (size_t)l * WVE, base, WVE, (int)(WVE / 8));
        split3w<<<(int)(WVE / 8 + 255) / 256, 256, 0, stream>>>(
            Wo + (size_t)l * WVE, base + 3 * WVE, WVE, (int)(WVE / 8));
        split3w<<<(int)(W1E / 8 + 255) / 256, 256, 0, stream>>>(
            W1 + (size_t)l * W1E, base + 6 * WVE, W1E, (int)(W1E / 8));
        split3w<<<(int)(W1E / 8 + 255) / 256, 256, 0, stream>>>(
            W2 + (size_t)l * W1E, base + 6 * WVE + 3 * W1E, W1E, (int)(W1E / 8));
    }
    if (q2_mfma) {
        split3w<<<(int)(WVE / 8 + 255) / 256, 256, 0, stream>>>(
            Wk + 1 * WVE, wk_pl, WVE, (int)(WVE / 8));
    }

    add_pe_new<<<(int)(NE / 8 + 255) / 256, 256, 0, stream>>>(
        q_embed, qa_embed, pe, xbuf, y_pl, NE, (int)(NE / 8));

    for (int l = 0; l < NL; l++) {
        ushort_t* wb = w_pl + (size_t)l * LW;
        ushort_t* Wv_pl = wb;
        ushort_t* Wo_pl = wb + 3 * WVE;
        ushort_t* W1_pl = wb + 6 * WVE;
        ushort_t* W2_pl = wb + 6 * WVE + 3 * W1E;

        // q projection:
        //   layer 1 (l==0): fp32 exact — structural p-tie exists, any noise flips it.
        //   layer 2 (l==1): split-6 MFMA — proven safe at ~1e-6 score noise.
        if (l == 1 && q2_mfma) {
            gemm3p<0, 0, 3><<<dim3(DIM / 128, M / 128), 256, 0, stream>>>(
                x_pl, NE, DIM, wk_pl, WVE, DIM, bk + (size_t)l * DIM,
                qbuf, nullptr, 0, DIM, DIM);
        } else {
            gemm_bt<0><<<dim3(DIM / 128, M / 128), 512, 0, stream>>>(
                xbuf, Wk + (size_t)l * WVE, bk + (size_t)l * DIM, qbuf, M, DIM, DIM);
        }
        if (l == 0) {
            gemm3p<0, 0, 3><<<dim3(DIM / 128, M / 128), 256, 0, stream>>>(
                y_pl, NE, DIM, Wv_pl, WVE, DIM, bv + (size_t)l * DIM,
                vbuf, nullptr, 0, DIM, DIM);
        } else {
            gemm3p<0, 0, 2><<<dim3(DIM / 128, M / 128), 256, 0, stream>>>(
                y_pl, NE, DIM, Wv_pl, WVE, DIM, bv + (size_t)l * DIM,
                vbuf, nullptr, 0, DIM, DIM);
        }
        transpose_v_kernel<<<dim3(8, BSZ * NH), 256, 0, stream>>>(vbuf, vt);
        scores128_kernel<<<dim3(10, BSZ * NH), 256, 0, stream>>>(qbuf, pbuf);
        softmax_topk_kernel<<<dim3(SEQ / 4, BSZ * NH), 256, 0, stream>>>(pbuf);
        if (l == 0) {
            mm6av_pl<3><<<dim3(4, BSZ * NH), 256, 0, stream>>>(pbuf, vt, o_pl, NE);
            gemm3p<0, 0, 3><<<dim3(DIM / 128, M / 128), 256, 0, stream>>>(
                o_pl, NE, DIM, Wo_pl, WVE, DIM, bo + (size_t)l * DIM,
                qbuf, nullptr, 0, DIM, DIM);
        } else {
            mm6av_pl<2><<<dim3(4, BSZ * NH), 256, 0, stream>>>(pbuf, vt, o_pl, NE);
            gemm3p<0, 0, 2><<<dim3(DIM / 128, M / 128), 256, 0, stream>>>(
                o_pl, NE, DIM, Wo_pl, WVE, DIM, bo + (size_t)l * DIM,
                qbuf, nullptr, 0, DIM, DIM);
        }
        add_ln_kernel<1><<<M, 64, 0, stream>>>(
            xbuf, qbuf, ln1w + (size_t)l * DIM, ln1b + (size_t)l * DIM,
            xbuf, x_pl, NE);
        if (l == 0) {
            gemm3p<1, 1, 3><<<dim3(DFFN / 128, M / 128), 256, 0, stream>>>(
                x_pl, NE, DIM, W1_pl, W1E, DIM, b1 + (size_t)l * DFFN,
                nullptr, h1_pl, (size_t)M * DFFN, DFFN, DIM);
            gemm3p<0, 0, 3><<<dim3(DIM / 128, M / 128), 256, 0, stream>>>(
                h1_pl, (size_t)M * DFFN, DFFN, W2_pl, W1E, DFFN, b2 + (size_t)l * DIM,
                vbuf, nullptr, 0, DIM, DFFN);
        } else {
            gemm3p<1, 1, 2><<<dim3(DFFN / 128, M / 128), 256, 0, stream>>>(
                x_pl, NE, DIM, W1_pl, W1E, DIM, b1 + (size_t)l * DFFN,
                nullptr, h1_pl, (size_t)M * DFFN, DFFN, DIM);
            gemm3p<0, 0, 2><<<dim3(DIM / 128, M / 128), 256, 0, stream>>>(
                h1_pl, (size_t)M * DFFN, DFFN, W2_pl, W1E, DFFN, b2 + (size_t)l * DIM,
                vbuf, nullptr, 0, DIM, DFFN);
        }
        // x = LN(x + ff); after layer 0 also emit x planes for layer-2's q-projection
        if (l == NL - 1) {
            add_ln_kernel<0><<<M, 64, 0, stream>>>(
                xbuf, vbuf, ln2w + (size_t)l * DIM, ln2b + (size_t)l * DIM,
                outx, nullptr, 0);
        } else if (q2_mfma) {
            add_ln_kernel<1><<<M, 64, 0, stream>>>(
                xbuf, vbuf, ln2w + (size_t)l * DIM, ln2b + (size_t)l * DIM,
                xbuf, x_pl, NE);
        } else {
            add_ln_kernel<0><<<M, 64, 0, stream>>>(
                xbuf, vbuf, ln2w + (size_t)l * DIM, ln2b + (size_t)l * DIM,
                xbuf, nullptr, 0);
        }
    }
}

// Round 17
// 1778.850 us; speedup vs baseline: 1.0994x; 1.0969x over previous
//
#include <hip/hip_runtime.h>
#include <hip/hip_bf16.h>
#include <math.h>

#define BSZ 32
#define SEQ 512
#define DIM 512
#define NH 8
#define DKH 64
#define DFFN 2048
#define NL 2
#define KIDX 5
#define NEGV -1e32f

typedef float f32x4 __attribute__((ext_vector_type(4)));
typedef short bf16x8 __attribute__((ext_vector_type(8)));
typedef unsigned short ushort_t;
typedef __attribute__((address_space(1))) void gvoid;
typedef __attribute__((address_space(3))) void lvoid;

// async global->LDS, 16B per lane; dest is wave-uniform base (+lane*16 by HW)
__device__ __forceinline__ void gload_lds16(const void* g, void* l) {
    __builtin_amdgcn_global_load_lds((gvoid*)(uintptr_t)g, (lvoid*)l, 16, 0, 0);
}

// ---------------- wave (64-lane) reduce helpers ----------------
__device__ __forceinline__ float wmaxf(float v) {
    #pragma unroll
    for (int m = 32; m > 0; m >>= 1) v = fmaxf(v, __shfl_xor(v, m));
    return v;
}
__device__ __forceinline__ float wsumf(float v) {
    #pragma unroll
    for (int m = 32; m > 0; m >>= 1) v += __shfl_xor(v, m);
    return v;
}
__device__ __forceinline__ int wsumi(int v) {
    #pragma unroll
    for (int m = 32; m > 0; m >>= 1) v += __shfl_xor(v, m);
    return v;
}

// ---------------- bf16 split helpers ----------------
__device__ __forceinline__ unsigned int bf16_rne(float x) {
    unsigned int u = __float_as_uint(x);
    return (u + 0x7fffu + ((u >> 16) & 1u)) >> 16;
}
__device__ __forceinline__ void split3_8(const float* xs, unsigned int* hh,
                                         unsigned int* hm, unsigned int* hl) {
    #pragma unroll
    for (int e = 0; e < 8; e++) {
        float x = xs[e];
        unsigned int h0 = bf16_rne(x);
        float r1 = x - __uint_as_float(h0 << 16);
        unsigned int h1 = bf16_rne(r1);
        float r2 = r1 - __uint_as_float(h1 << 16);
        hh[e] = h0; hm[e] = h1; hl[e] = bf16_rne(r2);
    }
}
__device__ __forceinline__ uint4 pack8(const unsigned int* h) {
    return make_uint4(h[0] | (h[1] << 16), h[2] | (h[3] << 16),
                      h[4] | (h[5] << 16), h[6] | (h[7] << 16));
}

__device__ __forceinline__ f32x4 mfma_bf16(bf16x8 a, bf16x8 b, f32x4 c) {
    return __builtin_amdgcn_mfma_f32_16x16x32_bf16(a, b, c, 0, 0, 0);
}

// ---------------- add_pe: x fp32 + y planes ----------------
__global__ void add_pe_new(const float* __restrict__ q, const float* __restrict__ qa,
                           const float* __restrict__ pe, float* __restrict__ x,
                           ushort_t* __restrict__ ypl, size_t yelems, int n8) {
    int i = blockIdx.x * 256 + threadIdx.x;
    if (i >= n8) return;
    size_t base = (size_t)i * 8;
    size_t pb = base & (size_t)(SEQ * DIM - 1);
    float4 a0 = *(const float4*)(q + base), a1 = *(const float4*)(q + base + 4);
    float4 b0 = *(const float4*)(qa + base), b1 = *(const float4*)(qa + base + 4);
    float4 p0 = *(const float4*)(pe + pb), p1 = *(const float4*)(pe + pb + 4);
    float4 x0 = make_float4(a0.x + p0.x, a0.y + p0.y, a0.z + p0.z, a0.w + p0.w);
    float4 x1 = make_float4(a1.x + p1.x, a1.y + p1.y, a1.z + p1.z, a1.w + p1.w);
    *(float4*)(x + base) = x0;
    *(float4*)(x + base + 4) = x1;
    float ys[8] = {b0.x + p0.x, b0.y + p0.y, b0.z + p0.z, b0.w + p0.w,
                   b1.x + p1.x, b1.y + p1.y, b1.z + p1.z, b1.w + p1.w};
    unsigned int hh[8], hm[8], hl[8];
    split3_8(ys, hh, hm, hl);
    *(uint4*)(ypl + base) = pack8(hh);
    *(uint4*)(ypl + yelems + base) = pack8(hm);
    *(uint4*)(ypl + 2 * yelems + base) = pack8(hl);
}

// ---------------- weight pre-split: fp32 -> 3 bf16 planes ----------------
__global__ void split3w(const float* __restrict__ W, ushort_t* __restrict__ out,
                        size_t elems, int n8) {
    int i = blockIdx.x * 256 + threadIdx.x;
    if (i >= n8) return;
    size_t base = (size_t)i * 8;
    float4 a0 = *(const float4*)(W + base), a1 = *(const float4*)(W + base + 4);
    float xs[8] = {a0.x, a0.y, a0.z, a0.w, a1.x, a1.y, a1.z, a1.w};
    unsigned int hh[8], hm[8], hl[8];
    split3_8(xs, hh, hm, hl);
    *(uint4*)(out + base) = pack8(hh);
    *(uint4*)(out + elems + base) = pack8(hm);
    *(uint4*)(out + 2 * elems + base) = pack8(hl);
}

// ---------------- fp32 vector GEMM (selection-critical layer-1 q; exact chains) ----------------
template <int RELU>
__global__ __launch_bounds__(512)
void gemm_bt(const float* __restrict__ A, const float* __restrict__ B,
             const float* __restrict__ bias, float* __restrict__ C,
             int M, int N, int K) {
    __shared__ float As[32][132];
    __shared__ float Bs[32][132];
    const int tid = threadIdx.x;
    const int tx = tid & 15, ty = tid >> 4;   // ty 0..31
    const int m0 = blockIdx.y * 128, n0 = blockIdx.x * 128;
    float acc[4][8] = {};
    for (int k0 = 0; k0 < K; k0 += 32) {
        #pragma unroll
        for (int s = tid; s < 1024; s += 512) {
            int r = (s & 15) | ((s >> 7) << 4);   // 2-way-free LDS write banks
            int c4 = (s >> 4) & 7;
            float4 va = *(const float4*)(A + (size_t)(m0 + r) * K + k0 + c4 * 4);
            As[c4 * 4 + 0][r] = va.x; As[c4 * 4 + 1][r] = va.y;
            As[c4 * 4 + 2][r] = va.z; As[c4 * 4 + 3][r] = va.w;
            float4 vb = *(const float4*)(B + (size_t)(n0 + r) * K + k0 + c4 * 4);
            Bs[c4 * 4 + 0][r] = vb.x; Bs[c4 * 4 + 1][r] = vb.y;
            Bs[c4 * 4 + 2][r] = vb.z; Bs[c4 * 4 + 3][r] = vb.w;
        }
        __syncthreads();
        #pragma unroll 8
        for (int kk = 0; kk < 32; kk++) {
            float a[4], b[8];
            *(float4*)&a[0] = *(const float4*)&As[kk][ty * 4];
            *(float4*)&b[0] = *(const float4*)&Bs[kk][tx * 8];
            *(float4*)&b[4] = *(const float4*)&Bs[kk][tx * 8 + 4];
            #pragma unroll
            for (int i = 0; i < 4; i++)
                #pragma unroll
                for (int j = 0; j < 8; j++)
                    acc[i][j] = fmaf(a[i], b[j], acc[i][j]);
        }
        __syncthreads();
    }
    float bv[8];
    *(float4*)&bv[0] = *(const float4*)(bias + n0 + tx * 8);
    *(float4*)&bv[4] = *(const float4*)(bias + n0 + tx * 8 + 4);
    #pragma unroll
    for (int i = 0; i < 4; i++) {
        float out[8];
        #pragma unroll
        for (int j = 0; j < 8; j++) {
            float v = acc[i][j] + bv[j];
            if (RELU) v = fmaxf(v, 0.f);
            out[j] = v;
        }
        float* cp = C + (size_t)(m0 + ty * 4 + i) * N + n0 + tx * 8;
        *(float4*)cp = *(float4*)&out[0];
        *(float4*)(cp + 4) = *(float4*)&out[4];
    }
}

// ---------------- fp32 scores (selection-critical, round-1 arithmetic) ----------------
__global__ __launch_bounds__(256)
void scores128_kernel(const float* __restrict__ q, float* __restrict__ pbuf) {
    const int bh = blockIdx.y, b = bh >> 3, h = bh & 7;
    const int x = blockIdx.x;
    const int it = (x >= 6) ? 3 : (x >= 3) ? 2 : (x >= 1) ? 1 : 0;
    const int jt = x - it * (it + 1) / 2;
    const int m0 = it * 128, n0 = jt * 128;
    __shared__ float Qi[64][132];
    __shared__ float Qj[64][132];
    const float* qbase = q + (size_t)b * SEQ * DIM + h * DKH;
    const int tid = threadIdx.x;
    for (int s = tid; s < 2048; s += 256) {
        int row = (s & 15) | ((s >> 8) << 4);
        int c4 = (s >> 4) & 15;
        float4 vi = *(const float4*)(qbase + (size_t)(m0 + row) * DIM + c4 * 4);
        Qi[c4 * 4 + 0][row] = vi.x; Qi[c4 * 4 + 1][row] = vi.y;
        Qi[c4 * 4 + 2][row] = vi.z; Qi[c4 * 4 + 3][row] = vi.w;
        float4 vj = *(const float4*)(qbase + (size_t)(n0 + row) * DIM + c4 * 4);
        Qj[c4 * 4 + 0][row] = vj.x; Qj[c4 * 4 + 1][row] = vj.y;
        Qj[c4 * 4 + 2][row] = vj.z; Qj[c4 * 4 + 3][row] = vj.w;
    }
    __syncthreads();
    const int tx = tid & 15, ty = tid >> 4;
    float acc[8][8] = {};
    #pragma unroll 4
    for (int d = 0; d < 64; d++) {
        float a[8], bb[8];
        *(float4*)&a[0] = *(const float4*)&Qi[d][ty * 8];
        *(float4*)&a[4] = *(const float4*)&Qi[d][ty * 8 + 4];
        *(float4*)&bb[0] = *(const float4*)&Qj[d][tx * 8];
        *(float4*)&bb[4] = *(const float4*)&Qj[d][tx * 8 + 4];
        #pragma unroll
        for (int i = 0; i < 8; i++)
            #pragma unroll
            for (int j = 0; j < 8; j++)
                acc[i][j] = fmaf(a[i], bb[j], acc[i][j]);
    }
    float* prow = pbuf + ((size_t)bh * SEQ + m0) * SEQ + n0;
    #pragma unroll
    for (int i = 0; i < 8; i++) {
        int gi = m0 + ty * 8 + i;
        #pragma unroll
        for (int jq = 0; jq < 2; jq++) {
            float o[4];
            #pragma unroll
            for (int j = 0; j < 4; j++) {
                int gj = n0 + tx * 8 + jq * 4 + j;
                o[j] = (gj < gi) ? acc[i][jq * 4 + j] * 0.125f : NEGV;
            }
            *(float4*)(prow + (size_t)(ty * 8 + i) * SEQ + tx * 8 + jq * 4) = *(float4*)o;
        }
    }
}

// ---------------- lean NP-plane bf16 GEMM (pre-split operands, async staging) ----------------
// NP=3: 6 products (split-6, fp32-fidelity). NP=2: 3 products. NP=1: plain bf16.
// Product orders for NP=2/3 are bitwise-identical to prior rounds.
template <int RELU, int OUTP, int NP>
__global__ __launch_bounds__(256) void gemm3p(
    const ushort_t* __restrict__ Apl, size_t Aelems, int lda,
    const ushort_t* __restrict__ Bpl, size_t Belems, int ldb,
    const float* __restrict__ bias,
    float* __restrict__ C, ushort_t* __restrict__ Cpl, size_t Celems,
    int ldc, int K) {
    constexpr int BB = NP * 512;               // uint4 idx of B region
    __shared__ uint4 lds[2 * NP * 512];
    const int tid = threadIdx.x, lane = tid & 63, wid = tid >> 6;
    const int wm = wid >> 1, wn = wid & 1;
    const int m0 = blockIdx.y * 128, n0 = blockIdx.x * 128;
    const int lrow = lane & 15, lkof = (lane >> 4) * 8;
    f32x4 acc[4][4] = {};
    for (int k0 = 0; k0 < K; k0 += 32) {
        #pragma unroll
        for (int t = 0; t < 4 * NP; t++) {
            int cc = wid + t * 4;              // 0 .. 16*NP-1
            bool isB = cc >= 8 * NP;
            int c2 = isB ? (cc - 8 * NP) : cc;
            int p = c2 >> 3, fi = c2 & 7;
            const ushort_t* pb = isB ? (Bpl + (size_t)p * Belems) : (Apl + (size_t)p * Aelems);
            int ld = isB ? ldb : lda;
            int r0 = isB ? n0 : m0;
            const ushort_t* src = pb + (size_t)(r0 + fi * 16 + lrow) * ld + k0 + lkof;
            gload_lds16(src, &lds[(isB ? BB : 0) + p * 512 + fi * 64]);
        }
        __syncthreads();
        const bf16x8* ldsb = (const bf16x8*)lds;
        bf16x8 afr[4][NP];
        #pragma unroll
        for (int fm = 0; fm < 4; fm++)
            #pragma unroll
            for (int p = 0; p < NP; p++)
                afr[fm][p] = ldsb[p * 512 + (wm * 4 + fm) * 64 + lane];
        #pragma unroll
        for (int fn = 0; fn < 4; fn++) {
            bf16x8 b0 = ldsb[BB + 0 * 512 + (wn * 4 + fn) * 64 + lane];
            bf16x8 b1, b2;
            if constexpr (NP >= 2) b1 = ldsb[BB + 1 * 512 + (wn * 4 + fn) * 64 + lane];
            if constexpr (NP == 3) b2 = ldsb[BB + 2 * 512 + (wn * 4 + fn) * 64 + lane];
            #pragma unroll
            for (int fm = 0; fm < 4; fm++) {
                f32x4 t = acc[fm][fn];
                if constexpr (NP == 3) {
                    t = mfma_bf16(afr[fm][0], b0, t);
                    t = mfma_bf16(afr[fm][1], b0, t);
                    t = mfma_bf16(afr[fm][2], b0, t);
                    t = mfma_bf16(afr[fm][0], b1, t);
                    t = mfma_bf16(afr[fm][1], b1, t);
                    t = mfma_bf16(afr[fm][0], b2, t);
                } else if constexpr (NP == 2) {
                    t = mfma_bf16(afr[fm][0], b0, t);
                    t = mfma_bf16(afr[fm][1], b0, t);
                    t = mfma_bf16(afr[fm][0], b1, t);
                } else {
                    t = mfma_bf16(afr[fm][0], b0, t);
                }
                acc[fm][fn] = t;
            }
        }
        __syncthreads();
    }
    #pragma unroll
    for (int fm = 0; fm < 4; fm++) {
        int row0 = m0 + (wm * 4 + fm) * 16 + (lane >> 4) * 4;
        #pragma unroll
        for (int fn = 0; fn < 4; fn++) {
            int col = n0 + (wn * 4 + fn) * 16 + (lane & 15);
            float bv = bias[col];
            f32x4 a = acc[fm][fn];
            #pragma unroll
            for (int r = 0; r < 4; r++) {
                int row = row0 + r;
                float val = a[r] + bv;
                if (RELU) val = fmaxf(val, 0.f);
                if constexpr (OUTP == 0) {
                    C[(size_t)row * ldc + col] = val;
                } else {
                    unsigned int h0 = bf16_rne(val);
                    size_t o = (size_t)row * ldc + col;
                    Cpl[o] = (ushort_t)h0;
                    if constexpr (NP >= 2) {
                        float r1 = val - __uint_as_float(h0 << 16);
                        unsigned int h1 = bf16_rne(r1);
                        Cpl[Celems + o] = (ushort_t)h1;
                        if constexpr (NP == 3) {
                            float r2 = r1 - __uint_as_float(h1 << 16);
                            Cpl[2 * Celems + o] = (ushort_t)bf16_rne(r2);
                        }
                    }
                }
            }
        }
    }
}

// ---------------- AV with NP-plane output (in-kernel split staging) ----------------
// kmax: rb>=1 tiles stop at their diagonal; rb==0 needs full K (rows 1..4 keep
// nonzero weight at ALL columns after the second softmax).
template <int NP>
__global__ __launch_bounds__(256) void mm6av_pl(const float* __restrict__ pbuf,
                                                const float* __restrict__ vt,
                                                ushort_t* __restrict__ Opl, size_t Oelems) {
    constexpr int BBASE = NP * 512;
    __shared__ uint4 lds[NP * 512 + NP * 256];
    const int tid = threadIdx.x, lane = tid & 63, wid = tid >> 6;
    const int bh = blockIdx.y, b = bh >> 3, h = bh & 7, rb = blockIdx.x;
    const int m0 = rb * 128;
    const float* A = pbuf + (size_t)bh * SEQ * SEQ;
    const float* B = vt + (size_t)bh * DKH * SEQ;
    const int kmax = rb ? (rb + 1) * 128 : SEQ;

    f32x4 acc[2][4] = {};
    for (int k0 = 0; k0 < kmax; k0 += 32) {
        for (int c = tid; c < 12 * 64; c += 256) {
            int fi = c >> 6, lc = c & 63;
            const float* src = (fi < 8)
                ? A + (size_t)(m0 + fi * 16 + (lc & 15)) * SEQ + k0 + (lc >> 4) * 8
                : B + (size_t)((fi - 8) * 16 + (lc & 15)) * SEQ + k0 + (lc >> 4) * 8;
            float4 x0 = *(const float4*)src;
            float4 x1 = *(const float4*)(src + 4);
            float xs[8] = {x0.x, x0.y, x0.z, x0.w, x1.x, x1.y, x1.z, x1.w};
            unsigned int hh[8], hm[8], hl[8];
            split3_8(xs, hh, hm, hl);
            int base, fstride;
            if (fi < 8) { base = fi * 64 + lc; fstride = 512; }
            else { base = BBASE + (fi - 8) * 64 + lc; fstride = 256; }
            lds[base] = pack8(hh);
            if constexpr (NP >= 2) lds[base + fstride] = pack8(hm);
            if constexpr (NP == 3) lds[base + 2 * fstride] = pack8(hl);
        }
        __syncthreads();
        const bf16x8* ldsb = (const bf16x8*)lds;
        bf16x8 afr[2][NP];
        #pragma unroll
        for (int fm = 0; fm < 2; fm++)
            #pragma unroll
            for (int p = 0; p < NP; p++)
                afr[fm][p] = ldsb[p * 512 + (wid * 2 + fm) * 64 + lane];
        #pragma unroll
        for (int fn = 0; fn < 4; fn++) {
            bf16x8 b0 = ldsb[BBASE + 0 * 256 + fn * 64 + lane];
            bf16x8 b1, b2;
            if constexpr (NP >= 2) b1 = ldsb[BBASE + 1 * 256 + fn * 64 + lane];
            if constexpr (NP == 3) b2 = ldsb[BBASE + 2 * 256 + fn * 64 + lane];
            #pragma unroll
            for (int fm = 0; fm < 2; fm++) {
                f32x4 t = acc[fm][fn];
                if constexpr (NP == 3) {
                    t = mfma_bf16(afr[fm][0], b0, t);
                    t = mfma_bf16(afr[fm][1], b0, t);
                    t = mfma_bf16(afr[fm][2], b0, t);
                    t = mfma_bf16(afr[fm][0], b1, t);
                    t = mfma_bf16(afr[fm][1], b1, t);
                    t = mfma_bf16(afr[fm][0], b2, t);
                } else if constexpr (NP == 2) {
                    t = mfma_bf16(afr[fm][0], b0, t);
                    t = mfma_bf16(afr[fm][1], b0, t);
                    t = mfma_bf16(afr[fm][0], b1, t);
                } else {
                    t = mfma_bf16(afr[fm][0], b0, t);
                }
                acc[fm][fn] = t;
            }
        }
        __syncthreads();
    }
    #pragma unroll
    for (int fm = 0; fm < 2; fm++) {
        int row0 = m0 + (wid * 2 + fm) * 16 + (lane >> 4) * 4;
        #pragma unroll
        for (int fn = 0; fn < 4; fn++) {
            int col = fn * 16 + (lane & 15);
            f32x4 a = acc[fm][fn];
            #pragma unroll
            for (int r = 0; r < 4; r++) {
                int row = row0 + r;
                float val = (row == 0) ? 0.f : a[r];
                unsigned int h0 = bf16_rne(val);
                size_t o = ((size_t)b * SEQ + row) * DIM + h * DKH + col;
                Opl[o] = (ushort_t)h0;
                if constexpr (NP >= 2) {
                    float r1 = val - __uint_as_float(h0 << 16);
                    unsigned int h1 = bf16_rne(r1);
                    Opl[Oelems + o] = (ushort_t)h1;
                    if constexpr (NP == 3) {
                        float r2 = r1 - __uint_as_float(h1 << 16);
                        Opl[2 * Oelems + o] = (ushort_t)bf16_rne(r2);
                    }
                }
            }
        }
    }
}

// ---------------- V transpose ----------------
__global__ __launch_bounds__(256) void transpose_v_kernel(const float* __restrict__ v,
                                                          float* __restrict__ vt) {
    const int bh = blockIdx.y, jt = blockIdx.x;
    const int b = bh >> 3, h = bh & 7;
    __shared__ float L[64][65];
    const int tid = threadIdx.x;
    for (int s = tid; s < 1024; s += 256) {
        int jj = s >> 4, d4 = s & 15;
        float4 x = *(const float4*)(v + ((size_t)(b * SEQ) + jt * 64 + jj) * DIM + h * DKH + d4 * 4);
        L[jj][d4 * 4 + 0] = x.x; L[jj][d4 * 4 + 1] = x.y;
        L[jj][d4 * 4 + 2] = x.z; L[jj][d4 * 4 + 3] = x.w;
    }
    __syncthreads();
    int d = tid >> 2, jq = tid & 3;
    float* dst = vt + ((size_t)bh * DKH + d) * SEQ + jt * 64 + jq * 16;
    #pragma unroll
    for (int c4 = 0; c4 < 4; c4++) {
        float4 o = make_float4(L[jq * 16 + c4 * 4 + 0][d], L[jq * 16 + c4 * 4 + 1][d],
                               L[jq * 16 + c4 * 4 + 2][d], L[jq * 16 + c4 * 4 + 3][d]);
        *(float4*)(dst + c4 * 4) = o;
    }
}

// ---------------- softmax -> top5 -> second softmax (4 rows per 256-thread block) ----------------
__global__ __launch_bounds__(256)
void softmax_topk_kernel(float* __restrict__ pbuf) {
    const int wid = threadIdx.x >> 6, lane = threadIdx.x & 63;
    const int i = blockIdx.x * 4 + wid;
    const size_t row = (size_t)blockIdx.y * SEQ + i;
    float* p = pbuf + row * SEQ;
    float v[8];
    {
        int j0 = lane * 4;
        if (j0 < i) {
            float4 x0 = *(const float4*)(p + j0);
            v[0] = (j0 + 0 < i) ? x0.x : NEGV;
            v[1] = (j0 + 1 < i) ? x0.y : NEGV;
            v[2] = (j0 + 2 < i) ? x0.z : NEGV;
            v[3] = (j0 + 3 < i) ? x0.w : NEGV;
        } else { v[0] = v[1] = v[2] = v[3] = NEGV; }
        int j1 = 256 + j0;
        if (j1 < i) {
            float4 x1 = *(const float4*)(p + j1);
            v[4] = (j1 + 0 < i) ? x1.x : NEGV;
            v[5] = (j1 + 1 < i) ? x1.y : NEGV;
            v[6] = (j1 + 2 < i) ? x1.z : NEGV;
            v[7] = (j1 + 3 < i) ? x1.w : NEGV;
        } else { v[4] = v[5] = v[6] = v[7] = NEGV; }
    }
    float lm = v[0];
    #pragma unroll
    for (int e = 1; e < 8; e++) lm = fmaxf(lm, v[e]);
    float m1 = wmaxf(lm);
    float ls = 0.f;
    #pragma unroll
    for (int e = 0; e < 8; e++) { v[e] = expf(v[e] - m1); ls += v[e]; }
    float Z = wsumf(ls);
    #pragma unroll
    for (int e = 0; e < 8; e++) v[e] = v[e] / Z;
    float thr = -INFINITY;
    if (i >= KIDX) {
        int remaining = KIDX;
        float cut = INFINITY;
        #pragma unroll 1
        for (int iter = 0; iter < KIDX; iter++) {
            float l2 = -INFINITY;
            #pragma unroll
            for (int e = 0; e < 8; e++) if (v[e] < cut) l2 = fmaxf(l2, v[e]);
            float m2 = wmaxf(l2);
            int lc = 0;
            #pragma unroll
            for (int e = 0; e < 8; e++) if (v[e] == m2) lc++;
            int c = wsumi(lc);
            if (c >= remaining) { thr = m2; break; }
            remaining -= c; cut = m2;
        }
    }
    float lpm = v[0];
    #pragma unroll
    for (int e = 1; e < 8; e++) lpm = fmaxf(lpm, v[e]);
    float pm = wmaxf(lpm);
    float t[8];
    float ls2 = 0.f;
    #pragma unroll
    for (int e = 0; e < 8; e++) {
        bool keep = (i >= KIDX) ? (v[e] >= thr) : true;
        t[e] = keep ? expf(v[e] - pm) : 0.f;
        ls2 += t[e];
    }
    float Z2 = wsumf(ls2);
    #pragma unroll
    for (int e = 0; e < 8; e++) t[e] = t[e] / Z2;
    *(float4*)(p + lane * 4) = make_float4(t[0], t[1], t[2], t[3]);
    *(float4*)(p + 256 + lane * 4) = make_float4(t[4], t[5], t[6], t[7]);
}

// ---------------- dst = LN(x + t)  (EMIT: also write 3 bf16 planes of dst) ----------------
template <int EMIT>
__global__ __launch_bounds__(64)
void add_ln_kernel(const float* __restrict__ x, const float* __restrict__ t,
                   const float* __restrict__ w, const float* __restrict__ b,
                   float* __restrict__ dst, ushort_t* __restrict__ dpl, size_t delems) {
    const size_t row = blockIdx.x;
    const int lane = threadIdx.x;
    const float* xr = x + row * DIM;
    const float* tr = t + row * DIM;
    float v[8];
    {
        float4 a0 = *(const float4*)(xr + lane * 4);
        float4 t0 = *(const float4*)(tr + lane * 4);
        float4 a1 = *(const float4*)(xr + 256 + lane * 4);
        float4 t1 = *(const float4*)(tr + 256 + lane * 4);
        v[0] = a0.x + t0.x; v[1] = a0.y + t0.y; v[2] = a0.z + t0.z; v[3] = a0.w + t0.w;
        v[4] = a1.x + t1.x; v[5] = a1.y + t1.y; v[6] = a1.z + t1.z; v[7] = a1.w + t1.w;
    }
    float ls = 0.f;
    #pragma unroll
    for (int e = 0; e < 8; e++) ls += v[e];
    float mean = wsumf(ls) / (float)DIM;
    float ld = 0.f;
    #pragma unroll
    for (int e = 0; e < 8; e++) { float d = v[e] - mean; ld += d * d; }
    float var = wsumf(ld) / (float)DIM;
    float den = sqrtf(var + 1e-5f);
    float wv[8], bv[8];
    *(float4*)&wv[0] = *(const float4*)(w + lane * 4);
    *(float4*)&wv[4] = *(const float4*)(w + 256 + lane * 4);
    *(float4*)&bv[0] = *(const float4*)(b + lane * 4);
    *(float4*)&bv[4] = *(const float4*)(b + 256 + lane * 4);
    float o[8];
    #pragma unroll
    for (int e = 0; e < 8; e++) o[e] = (v[e] - mean) / den * wv[e] + bv[e];
    float* dr = dst + row * DIM;
    *(float4*)(dr + lane * 4) = make_float4(o[0], o[1], o[2], o[3]);
    *(float4*)(dr + 256 + lane * 4) = make_float4(o[4], o[5], o[6], o[7]);
    if constexpr (EMIT) {
        unsigned int hh[8], hm[8], hl[8];
        split3_8(o, hh, hm, hl);
        size_t base0 = row * DIM + lane * 4;
        size_t base1 = base0 + 256;
        #pragma unroll
        for (int p = 0; p < 3; p++) {
            const unsigned int* hp = (p == 0) ? hh : (p == 1) ? hm : hl;
            *(uint2*)(dpl + p * delems + base0) =
                make_uint2(hp[0] | (hp[1] << 16), hp[2] | (hp[3] << 16));
            *(uint2*)(dpl + p * delems + base1) =
                make_uint2(hp[4] | (hp[5] << 16), hp[6] | (hp[7] << 16));
        }
    }
}

extern "C" void kernel_launch(void* const* d_in, const int* in_sizes, int n_in,
                              void* d_out, int out_size, void* d_ws, size_t ws_size,
                              hipStream_t stream) {
    const float* q_embed = (const float*)d_in[0];
    const float* qa_embed = (const float*)d_in[1];
    const float* pe = (const float*)d_in[2];
    const float* Wk = (const float*)d_in[3];
    const float* bk = (const float*)d_in[4];
    const float* Wv = (const float*)d_in[5];
    const float* bv = (const float*)d_in[6];
    const float* Wo = (const float*)d_in[7];
    const float* bo = (const float*)d_in[8];
    const float* W1 = (const float*)d_in[9];
    const float* b1 = (const float*)d_in[10];
    const float* W2 = (const float*)d_in[11];
    const float* b2 = (const float*)d_in[12];
    const float* ln1w = (const float*)d_in[13];
    const float* ln1b = (const float*)d_in[14];
    const float* ln2w = (const float*)d_in[15];
    const float* ln2b = (const float*)d_in[16];

    float* outx = (float*)d_out;
    const size_t NE = (size_t)BSZ * SEQ * DIM;   // 8388608
    float* pbuf = outx + NE;
    float* ws = (float*)d_ws;
    const int M = BSZ * SEQ;

    // ===================== pre-split planes path (round-8 proven layout) =====================
    float* xbuf = ws;
    float* qbuf = ws + NE;
    float* vbuf = ws + 2 * NE;
    ushort_t* y_pl = (ushort_t*)(ws + 3 * NE);
    ushort_t* x_pl = (ushort_t*)(ws + 4 * NE + NE / 2);
    ushort_t* w_pl = (ushort_t*)(ws + 6 * NE);
    float* vt = ws + 7 * NE;
    ushort_t* o_pl = (ushort_t*)(ws + 8 * NE);
    ushort_t* h1_pl = (ushort_t*)(ws + 7 * NE);   // sequential reuse with vt/o_pl
    ushort_t* wk_pl = (ushort_t*)(ws + 13 * NE);  // Wk[1] planes (layer-2 q only)

    const size_t WVE = (size_t)DIM * DIM;      // 262144
    const size_t W1E = (size_t)DFFN * DIM;     // 1048576
    const size_t LW = 3 * (WVE + WVE + W1E + W1E);

    // layer-2 q via split-6 MFMA requires 13NE floats + 3*WVE ushorts of ws
    const bool q2_mfma = ws_size >= (13 * NE * sizeof(float) + 3 * WVE * sizeof(ushort_t));

    for (int l = 0; l < NL; l++) {
        ushort_t* base = w_pl + (size_t)l * LW;
        split3w<<<(int)(WVE / 8 + 255) / 256, 256, 0, stream>>>(
            Wv + (size_t)l * WVE, base, WVE, (int)(WVE / 8));
        split3w<<<(int)(WVE / 8 + 255) / 256, 256, 0, stream>>>(
            Wo + (size_t)l * WVE, base + 3 * WVE, WVE, (int)(WVE / 8));
        split3w<<<(int)(W1E / 8 + 255) / 256, 256, 0, stream>>>(
            W1 + (size_t)l * W1E, base + 6 * WVE, W1E, (int)(W1E / 8));
        split3w<<<(int)(W1E / 8 + 255) / 256, 256, 0, stream>>>(
            W2 + (size_t)l * W1E, base + 6 * WVE + 3 * W1E, W1E, (int)(W1E / 8));
    }
    if (q2_mfma) {
        split3w<<<(int)(WVE / 8 + 255) / 256, 256, 0, stream>>>(
            Wk + 1 * WVE, wk_pl, WVE, (int)(WVE / 8));
    }

    add_pe_new<<<(int)(NE / 8 + 255) / 256, 256, 0, stream>>>(
        q_embed, qa_embed, pe, xbuf, y_pl, NE, (int)(NE / 8));

    for (int l = 0; l < NL; l++) {
        ushort_t* wb = w_pl + (size_t)l * LW;
        ushort_t* Wv_pl = wb;
        ushort_t* Wo_pl = wb + 3 * WVE;
        ushort_t* W1_pl = wb + 6 * WVE;
        ushort_t* W2_pl = wb + 6 * WVE + 3 * W1E;

        // q projection:
        //   layer 1 (l==0): fp32 exact — structural p-tie exists, any noise flips it.
        //   layer 2 (l==1): split-6 MFMA — proven safe at ~1e-6 score noise.
        if (l == 1 && q2_mfma) {
            gemm3p<0, 0, 3><<<dim3(DIM / 128, M / 128), 256, 0, stream>>>(
                x_pl, NE, DIM, wk_pl, WVE, DIM, bk + (size_t)l * DIM,
                qbuf, nullptr, 0, DIM, DIM);
        } else {
            gemm_bt<0><<<dim3(DIM / 128, M / 128), 512, 0, stream>>>(
                xbuf, Wk + (size_t)l * WVE, bk + (size_t)l * DIM, qbuf, M, DIM, DIM);
        }
        // value path: l0 split-6 (feeds layer-2 selection via x); l1 plain bf16
        // (feeds ONLY the x output; error ~1-2 bf16 ULP vs 8-ULP threshold).
        if (l == 0) {
            gemm3p<0, 0, 3><<<dim3(DIM / 128, M / 128), 256, 0, stream>>>(
                y_pl, NE, DIM, Wv_pl, WVE, DIM, bv + (size_t)l * DIM,
                vbuf, nullptr, 0, DIM, DIM);
        } else {
            gemm3p<0, 0, 1><<<dim3(DIM / 128, M / 128), 256, 0, stream>>>(
                y_pl, NE, DIM, Wv_pl, WVE, DIM, bv + (size_t)l * DIM,
                vbuf, nullptr, 0, DIM, DIM);
        }
        transpose_v_kernel<<<dim3(8, BSZ * NH), 256, 0, stream>>>(vbuf, vt);
        scores128_kernel<<<dim3(10, BSZ * NH), 256, 0, stream>>>(qbuf, pbuf);
        softmax_topk_kernel<<<dim3(SEQ / 4, BSZ * NH), 256, 0, stream>>>(pbuf);
        if (l == 0) {
            mm6av_pl<3><<<dim3(4, BSZ * NH), 256, 0, stream>>>(pbuf, vt, o_pl, NE);
            gemm3p<0, 0, 3><<<dim3(DIM / 128, M / 128), 256, 0, stream>>>(
                o_pl, NE, DIM, Wo_pl, WVE, DIM, bo + (size_t)l * DIM,
                qbuf, nullptr, 0, DIM, DIM);
        } else {
            mm6av_pl<1><<<dim3(4, BSZ * NH), 256, 0, stream>>>(pbuf, vt, o_pl, NE);
            gemm3p<0, 0, 1><<<dim3(DIM / 128, M / 128), 256, 0, stream>>>(
                o_pl, NE, DIM, Wo_pl, WVE, DIM, bo + (size_t)l * DIM,
                qbuf, nullptr, 0, DIM, DIM);
        }
        add_ln_kernel<1><<<M, 64, 0, stream>>>(
            xbuf, qbuf, ln1w + (size_t)l * DIM, ln1b + (size_t)l * DIM,
            xbuf, x_pl, NE);
        if (l == 0) {
            gemm3p<1, 1, 3><<<dim3(DFFN / 128, M / 128), 256, 0, stream>>>(
                x_pl, NE, DIM, W1_pl, W1E, DIM, b1 + (size_t)l * DFFN,
                nullptr, h1_pl, (size_t)M * DFFN, DFFN, DIM);
            gemm3p<0, 0, 3><<<dim3(DIM / 128, M / 128), 256, 0, stream>>>(
                h1_pl, (size_t)M * DFFN, DFFN, W2_pl, W1E, DFFN, b2 + (size_t)l * DIM,
                vbuf, nullptr, 0, DIM, DFFN);
        } else {
            gemm3p<1, 1, 1><<<dim3(DFFN / 128, M / 128), 256, 0, stream>>>(
                x_pl, NE, DIM, W1_pl, W1E, DIM, b1 + (size_t)l * DFFN,
                nullptr, h1_pl, (size_t)M * DFFN, DFFN, DIM);
            gemm3p<0, 0, 1><<<dim3(DIM / 128, M / 128), 256, 0, stream>>>(
                h1_pl, (size_t)M * DFFN, DFFN, W2_pl, W1E, DFFN, b2 + (size_t)l * DIM,
                vbuf, nullptr, 0, DIM, DFFN);
        }
        // x = LN(x + ff); after layer 0 also emit x planes for layer-2's q-projection
        if (l == NL - 1) {
            add_ln_kernel<0><<<M, 64, 0, stream>>>(
                xbuf, vbuf, ln2w + (size_t)l * DIM, ln2b + (size_t)l * DIM,
                outx, nullptr, 0);
        } else if (q2_mfma) {
            add_ln_kernel<1><<<M, 64, 0, stream>>>(
                xbuf, vbuf, ln2w + (size_t)l * DIM, ln2b + (size_t)l * DIM,
                xbuf, x_pl, NE);
        } else {
            add_ln_kernel<0><<<M, 64, 0, stream>>>(
                xbuf, vbuf, ln2w + (size_t)l * DIM, ln2b + (size_t)l * DIM,
                xbuf, nullptr, 0);
        }
    }
}